// Round 7
// baseline (277.342 us; speedup 1.0000x reference)
//
#include <hip/hip_runtime.h>
#include <hip/hip_bf16.h>

// N=20000 nodes, E=200000 edges, H=8, C=256, IN=256, OUT=250, H*C=2048.
// R7: BK=128 GEMM (16 serial K-steps instead of 64; latency-bound chain 4x shorter),
//     m97-style single-buffer staging; alpha+zmix fused (wsoft folded into wmixT,
//     which is now built AFTER headw). Chunk XOR (row&7) keeps b128 reads balanced.

typedef __attribute__((ext_vector_type(8))) short short8v;
typedef __attribute__((ext_vector_type(4))) float float4v;

__device__ __forceinline__ unsigned f2bfu(float f) {
  unsigned u = __float_as_uint(f);
  return (u + 0x7fffu + ((u >> 16) & 1u)) >> 16;  // RNE f32 -> bf16
}
__device__ __forceinline__ float bfu_lo(unsigned u) { return __uint_as_float(u << 16); }
__device__ __forceinline__ float bfu_hi(unsigned u) { return __uint_as_float(u & 0xffff0000u); }
__device__ __forceinline__ unsigned pack2(float a, float b) { return f2bfu(a) | (f2bfu(b) << 16); }

__device__ __forceinline__ void ld8(const float* p, float* v) {
  float4 a = ((const float4*)p)[0], b = ((const float4*)p)[1];
  v[0] = a.x; v[1] = a.y; v[2] = a.z; v[3] = a.w;
  v[4] = b.x; v[5] = b.y; v[6] = b.z; v[7] = b.w;
}
__device__ __forceinline__ void st8(float* p, const float* v) {
  ((float4*)p)[0] = make_float4(v[0], v[1], v[2], v[3]);
  ((float4*)p)[1] = make_float4(v[4], v[5], v[6], v[7]);
}

__device__ __forceinline__ void gll16(const void* g, void* l) {
  __builtin_amdgcn_global_load_lds(
      (__attribute__((address_space(1))) void*)const_cast<void*>(g),
      (__attribute__((address_space(3))) void*)(l), 16, 0, 0);
}

// ---------------- small prep kernels ----------------

// out[c][r] = bf16(in[r][c]); zero-pads columns c in [Cc, Cpad)
__global__ void transpose_kernel(const float* __restrict__ in, short* __restrict__ out,
                                 int R, int Cc, int Cpad) {
  __shared__ float tile[32][33];
  int tx = threadIdx.x, ty = threadIdx.y;
  int c0 = blockIdx.x * 32, r0 = blockIdx.y * 32;
  #pragma unroll
  for (int j = ty; j < 32; j += 8) {
    int r = r0 + j, c = c0 + tx;
    tile[j][tx] = (r < R && c < Cc) ? in[(size_t)r * Cc + c] : 0.f;
  }
  __syncthreads();
  #pragma unroll
  for (int j = ty; j < 32; j += 8) {
    int c = c0 + j, r = r0 + tx;
    if (c < Cpad && r < R) out[(size_t)c * R + r] = (short)f2bfu(tile[tx][j]);
  }
}

// wmixT[c][h*256+k] = bf16(wsoft[h] * W_gat[k][h*256+c])  (scaled per-head transpose)
__global__ void wmix_kernel(const float* __restrict__ W, const float* __restrict__ wsoft,
                            short* __restrict__ out) {
  __shared__ float tile[32][33];
  int tx = threadIdx.x, ty = threadIdx.y;
  int h = blockIdx.z;
  float wh = wsoft[h];
  int c0 = blockIdx.x * 32, k0 = blockIdx.y * 32;
  #pragma unroll
  for (int j = ty; j < 32; j += 8)
    tile[j][tx] = W[(size_t)(k0 + j) * 2048 + h * 256 + c0 + tx];
  __syncthreads();
  #pragma unroll
  for (int j = ty; j < 32; j += 8)
    out[(size_t)(c0 + j) * 2048 + h * 256 + k0 + tx] = (short)f2bfu(wh * tile[tx][j]);
}

// ws_s[k*8+h] = sum_c W[k][h*256+c]*att_src[h][c]; ws_r = plain row-chunk sum
__global__ void prepws_kernel(const float* __restrict__ W, const float* __restrict__ att_s,
                              const float* __restrict__ att_d, float* __restrict__ ws_s,
                              float* __restrict__ ws_d, float* __restrict__ ws_r) {
  int g = blockIdx.x * 256 + threadIdx.x;  // 0..2047
  int k = g >> 3, h = g & 7;
  const float* wr = W + (size_t)k * 2048 + h * 256;
  const float* as = att_s + h * 256;
  const float* ad = att_d + h * 256;
  float s = 0.f, dd = 0.f, r = 0.f;
  for (int c = 0; c < 256; ++c) {
    float wv = wr[c];
    s += wv * as[c];
    dd += wv * ad[c];
    r += wv;
  }
  ws_s[g] = s;
  ws_d[g] = dd;
  ws_r[g] = r;
}

// a_s/a_d/rs[n][h] = x[n,:] . ws_*[:,h] (f32 exact); also emits x_bf (bf16 of x)
__global__ __launch_bounds__(256) void asd_kernel(const float* __restrict__ x,
    const float* __restrict__ ws_s, const float* __restrict__ ws_d,
    const float* __restrict__ ws_r, float* __restrict__ a_s,
    float* __restrict__ a_d, float* __restrict__ rs, short* __restrict__ x_bf) {
  __shared__ float ls[2048], ld2[2048], lr[2048];
  int tid = threadIdx.x;
  for (int i = tid; i < 2048; i += 256) { ls[i] = ws_s[i]; ld2[i] = ws_d[i]; lr[i] = ws_r[i]; }
  __syncthreads();
  int node = blockIdx.x * 32 + (tid >> 3);
  int h = tid & 7;
  const float4* xr = (const float4*)(x + (size_t)node * 256);
  float as = 0.f, ad = 0.f, rr = 0.f;
  for (int k4 = 0; k4 < 64; ++k4) {
    float4 v = xr[k4];
    int k8 = k4 * 32 + h;
    as += v.x * ls[k8] + v.y * ls[k8 + 8] + v.z * ls[k8 + 16] + v.w * ls[k8 + 24];
    ad += v.x * ld2[k8] + v.y * ld2[k8 + 8] + v.z * ld2[k8 + 16] + v.w * ld2[k8 + 24];
    rr += v.x * lr[k8] + v.y * lr[k8 + 8] + v.z * lr[k8 + 16] + v.w * lr[k8 + 24];
    if ((k4 & 7) == h) {  // this thread owns the bf16 write of chunk k4
      uint2 ov;
      ov.x = pack2(v.x, v.y);
      ov.y = pack2(v.z, v.w);
      *(uint2*)(x_bf + (size_t)node * 256 + k4 * 4) = ov;
    }
  }
  a_s[node * 8 + h] = as;
  a_d[node * 8 + h] = ad;
  rs[node * 8 + h] = rr;
}

// ---------------- bf16 MFMA GEMM (64x256 tile, BK=128, 4 waves) ----------------
// C[M][256] = A[M][K] * BT[256][K]^T ; wave w owns output cols w*64..w*64+63.
// LDS [row][128] shorts, row stride 256B; chunk XOR (row&7) balances b128 reads.
// EPI=1: f32 store + bias, col<Nout.  EPI=2: bf16 store of relu(acc+bias+xres).
template <int EPI>
__global__ __launch_bounds__(256, 2) void gemm_kernel(
    const short* __restrict__ A, const short* __restrict__ BT,
    int M, int K,
    short* __restrict__ Cb, float* __restrict__ Cf,
    const float* __restrict__ bias, const float* __restrict__ xres, int Nout) {
  __shared__ short lA[64 * 128];    // 16 KB
  __shared__ short lB[256 * 128];   // 64 KB
  int tid = threadIdx.x;
  int wave = tid >> 6, lane = tid & 63;
  int m0 = blockIdx.x << 6;
  int lr = lane & 15, lq = lane >> 4;
  int lrow4 = lane >> 4;            // 0..3 row-within-stage
  int pch = lane & 15;              // physical 16B chunk within row

  float4v acc[4][4];
  #pragma unroll
  for (int i = 0; i < 4; ++i)
    #pragma unroll
    for (int j = 0; j < 4; ++j) acc[i][j] = (float4v){0.f, 0.f, 0.f, 0.f};

  // per-lane global element offsets for staging (invariant part)
  int offA[4];
  #pragma unroll
  for (int it = 0; it < 4; ++it) {
    int rowl = wave * 16 + it * 4 + lrow4;          // local row 0..63
    int grow = m0 + rowl;
    if (grow >= M) grow = M - 1;                    // clamp; masked at store
    int logical = pch ^ (rowl & 7);
    offA[it] = grow * K + logical * 8;
  }
  int offB[16];
  #pragma unroll
  for (int it = 0; it < 16; ++it) {
    int rowb = wave * 64 + it * 4 + lrow4;          // 0..255 (col of C)
    int logical = pch ^ (rowb & 7);
    offB[it] = rowb * K + logical * 8;
  }

  int nk = K >> 7;
  for (int t = 0; t < nk; ++t) {
    int k0 = t << 7;
    __syncthreads();
    #pragma unroll
    for (int it = 0; it < 4; ++it)
      gll16(A + offA[it] + k0, lA + (wave * 16 + it * 4) * 128);
    #pragma unroll
    for (int it = 0; it < 16; ++it)
      gll16(BT + offB[it] + k0, lB + (wave * 64 + it * 4) * 128);
    __syncthreads();
    #pragma unroll
    for (int ks = 0; ks < 4; ++ks) {
      int phys = ((ks * 4 + lq) ^ (lr & 7)) * 8;
      short8v af[4], bfv[4];
      #pragma unroll
      for (int i = 0; i < 4; ++i)
        af[i] = *(const short8v*)(lA + (i * 16 + lr) * 128 + phys);
      #pragma unroll
      for (int j = 0; j < 4; ++j)
        bfv[j] = *(const short8v*)(lB + (wave * 64 + j * 16 + lr) * 128 + phys);
      #pragma unroll
      for (int i = 0; i < 4; ++i)
        #pragma unroll
        for (int j = 0; j < 4; ++j)
          acc[i][j] = __builtin_amdgcn_mfma_f32_16x16x32_bf16(af[i], bfv[j], acc[i][j], 0, 0, 0);
    }
  }

  #pragma unroll
  for (int i = 0; i < 4; ++i) {
    #pragma unroll
    for (int jj = 0; jj < 4; ++jj) {
      int row = m0 + i * 16 + lq * 4 + jj;  // C/D: row=(l>>4)*4+reg, col=l&15
      if (row >= M) continue;
      #pragma unroll
      for (int j = 0; j < 4; ++j) {
        int col = wave * 64 + j * 16 + lr;
        float v = acc[i][j][jj];
        if (EPI == 1) {
          if (col < Nout) Cf[(size_t)row * Nout + col] = v + bias[col];
        } else {
          float o = v + bias[col] + xres[(size_t)row * 256 + col];
          Cb[(size_t)row * 256 + col] = (short)f2bfu(fmaxf(o, 0.f));
        }
      }
    }
  }
}

// ---------------- CSR build ----------------

__global__ void hist_kernel(const int* __restrict__ ei, int* __restrict__ deg, int E) {
  int e = blockIdx.x * 256 + threadIdx.x;
  if (e < E) atomicAdd(&deg[ei[E + e]], 1);
}

// single block, 1024 threads, 20 elems/thread local scan + one 1024-wide scan
__global__ __launch_bounds__(1024) void scan_kernel(const int* __restrict__ deg,
                                                    int* __restrict__ rowptr,
                                                    int* __restrict__ cursor, int n) {
  __shared__ int part[1024];
  int t = threadIdx.x;
  int base = t * 20;
  int loc[20];
  int run = 0;
  #pragma unroll
  for (int j = 0; j < 20; ++j) {
    int idx = base + j;
    int v = (idx < n) ? deg[idx] : 0;
    loc[j] = run;
    run += v;
  }
  part[t] = run;
  __syncthreads();
  for (int off = 1; off < 1024; off <<= 1) {
    int add = (t >= off) ? part[t - off] : 0;
    __syncthreads();
    part[t] += add;
    __syncthreads();
  }
  int off0 = (t > 0) ? part[t - 1] : 0;
  #pragma unroll
  for (int j = 0; j < 20; ++j) {
    int idx = base + j;
    if (idx < n) {
      int v = off0 + loc[j];
      rowptr[idx] = v;
      cursor[idx] = v;
    }
  }
  if (t == 1023) rowptr[n] = part[1023];
}

__global__ void scatter_kernel(const int* __restrict__ ei, int* __restrict__ cursor,
                               int* __restrict__ csr_src, int E) {
  int e = blockIdx.x * 256 + threadIdx.x;
  if (e < E) {
    int pos = atomicAdd(&cursor[ei[E + e]], 1);
    csr_src[pos] = ei[e];
  }
}

// ---------------- fused per-dst softmax + z-aggregate (wave per dst) ----------------
// u[d][h*256+k] = sum_e alpha_eh x_bf[src][k]  (UNFOLDED: wsoft applied in wmixT)
// pp[d][h] = sum_e alpha_eh rs[src][h]
__global__ __launch_bounds__(256) void alphaz_kernel(
    const short* __restrict__ x_bf, const float* __restrict__ a_s,
    const float* __restrict__ a_d, const float* __restrict__ rs,
    const int* __restrict__ rowptr, const int* __restrict__ csr,
    short* __restrict__ u, float* __restrict__ pp) {
  int d = (blockIdx.x * 256 + threadIdx.x) >> 6;
  int lane = threadIdx.x & 63;
  int beg = rowptr[d];
  int deg = rowptr[d + 1] - beg;

  float ad[8], m[8], s[8];
  ld8(a_d + (size_t)d * 8, ad);
  {
    float t[8];
    ld8(a_s + (size_t)d * 8, t);
    #pragma unroll
    for (int h = 0; h < 8; ++h) {
      float e = t[h] + ad[h];
      e = (e > 0.f) ? e : 0.2f * e;
      m[h] = e;   // self edge seeds the max
      s[h] = 1.f;
    }
  }

  // pass 1: online max/sum, lane-parallel over edges
  for (int base = 0; base < deg; base += 64) {
    int i = base + lane;
    bool act = i < deg;
    int src = act ? csr[beg + i] : 0;
    float e[8];
    {
      float t[8];
      ld8(a_s + (size_t)src * 8, t);
      #pragma unroll
      for (int h = 0; h < 8; ++h) {
        float v = t[h] + ad[h];
        v = (v > 0.f) ? v : 0.2f * v;
        e[h] = act ? v : -1e30f;
      }
    }
    float cm[8];
    #pragma unroll
    for (int h = 0; h < 8; ++h) cm[h] = e[h];
    #pragma unroll
    for (int off = 1; off < 64; off <<= 1)
      #pragma unroll
      for (int h = 0; h < 8; ++h) cm[h] = fmaxf(cm[h], __shfl_xor(cm[h], off));
    float nm[8], ex[8];
    #pragma unroll
    for (int h = 0; h < 8; ++h) nm[h] = fmaxf(m[h], cm[h]);
    #pragma unroll
    for (int h = 0; h < 8; ++h) ex[h] = act ? __expf(e[h] - nm[h]) : 0.f;
    #pragma unroll
    for (int off = 1; off < 64; off <<= 1)
      #pragma unroll
      for (int h = 0; h < 8; ++h) ex[h] += __shfl_xor(ex[h], off);
    #pragma unroll
    for (int h = 0; h < 8; ++h) {
      s[h] = s[h] * __expf(m[h] - nm[h]) + ex[h];
      m[h] = nm[h];
    }
  }

  float inv[8];
  #pragma unroll
  for (int h = 0; h < 8; ++h) inv[h] = 1.f / (s[h] + 1e-16f);

  // pass 2: wave-serial over nb = deg+1 edges (self last), prefetched.
  // alpha recomputed wave-redundantly (broadcast loads), accumulate x rows + pp.
  float acc[8][4];
  #pragma unroll
  for (int h = 0; h < 8; ++h)
    #pragma unroll
    for (int j = 0; j < 4; ++j) acc[h][j] = 0.f;
  float p[8] = {0, 0, 0, 0, 0, 0, 0, 0};

  int nb = deg + 1;
  int src_c = (deg > 0) ? csr[beg] : d;
  float asv[8], rsv[8];
  ld8(a_s + (size_t)src_c * 8, asv);
  ld8(rs + (size_t)src_c * 8, rsv);
  uint2 v_c = *(const uint2*)(x_bf + (size_t)src_c * 256 + lane * 4);

  for (int i = 0; i < nb; ++i) {
    float al[8];
    #pragma unroll
    for (int h = 0; h < 8; ++h) {
      float e = asv[h] + ad[h];
      e = (e > 0.f) ? e : 0.2f * e;
      al[h] = __expf(e - m[h]) * inv[h];
    }
    int j = i + 1;
    float asn[8], rsn[8];
    uint2 v_n;
    bool has = j < nb;
    if (has) {
      int sn = (j < deg) ? csr[beg + j] : d;
      ld8(a_s + (size_t)sn * 8, asn);
      ld8(rs + (size_t)sn * 8, rsn);
      v_n = *(const uint2*)(x_bf + (size_t)sn * 256 + lane * 4);
    }
    float xv0 = bfu_lo(v_c.x), xv1 = bfu_hi(v_c.x);
    float xv2 = bfu_lo(v_c.y), xv3 = bfu_hi(v_c.y);
    #pragma unroll
    for (int h = 0; h < 8; ++h) {
      float a = al[h];
      acc[h][0] += a * xv0;
      acc[h][1] += a * xv1;
      acc[h][2] += a * xv2;
      acc[h][3] += a * xv3;
      p[h] += a * rsv[h];
    }
    if (has) {
      #pragma unroll
      for (int h = 0; h < 8; ++h) { asv[h] = asn[h]; rsv[h] = rsn[h]; }
      v_c = v_n;
    }
  }

  #pragma unroll
  for (int h = 0; h < 8; ++h) {
    uint2 ov;
    ov.x = pack2(acc[h][0], acc[h][1]);
    ov.y = pack2(acc[h][2], acc[h][3]);
    *(uint2*)(u + (size_t)d * 2048 + h * 256 + lane * 4) = ov;
  }
  if (lane == 0) st8(pp + (size_t)d * 8, p);
}

// ---------------- pooled reduction ----------------
__global__ __launch_bounds__(256) void reduce_pp_kernel(const float* __restrict__ pp,
                                                        float* __restrict__ pooled) {
  int tid = threadIdx.x;
  float loc[8] = {0, 0, 0, 0, 0, 0, 0, 0};
  for (int r = blockIdx.x * 256 + tid; r < 20000; r += 80 * 256) {
    float t[8];
    ld8(pp + (size_t)r * 8, t);
    #pragma unroll
    for (int h = 0; h < 8; ++h) loc[h] += t[h];
  }
  #pragma unroll
  for (int off = 1; off < 64; off <<= 1)
    #pragma unroll
    for (int h = 0; h < 8; ++h) loc[h] += __shfl_xor(loc[h], off);
  __shared__ float sred[4][8];
  int wave = tid >> 6, lane = tid & 63;
  if (lane == 0) {
    #pragma unroll
    for (int h = 0; h < 8; ++h) sred[wave][h] = loc[h];
  }
  __syncthreads();
  if (tid < 8) {
    atomicAdd(&pooled[tid], sred[0][tid] + sred[1][tid] + sred[2][tid] + sred[3][tid]);
  }
}

// ---------------- head softmax weights ----------------
__global__ __launch_bounds__(256) void headw_kernel(const float* __restrict__ pooled,
    const float* __restrict__ b_gat, const float* __restrict__ conv_w,
    const float* __restrict__ conv_b, float* __restrict__ wsoft) {
  __shared__ float sb[8];
  int t = threadIdx.x;
  float v = 0.f;
  #pragma unroll
  for (int j = 0; j < 8; ++j) v += b_gat[t * 8 + j];
  #pragma unroll
  for (int off = 1; off < 32; off <<= 1) v += __shfl_xor(v, off);
  if ((t & 31) == 0 && t < 256) sb[t >> 5] = v;
  __syncthreads();
  if (t == 0) {
    const float invNC = 1.0f / (20000.0f * 256.0f);
    float g[8];
    float mx = -1e30f;
    #pragma unroll
    for (int h = 0; h < 8; ++h) {
      float pm = (pooled[h] + 20000.0f * sb[h]) * invNC;
      float gv = pm * conv_w[0] + conv_b[0];
      gv = fmaxf(gv, 0.f);
      g[h] = gv;
      mx = fmaxf(mx, gv);
    }
    float ssum = 0.f;
    #pragma unroll
    for (int h = 0; h < 8; ++h) { g[h] = __expf(g[h] - mx); ssum += g[h]; }
    #pragma unroll
    for (int h = 0; h < 8; ++h) wsoft[h] = g[h] / ssum;
  }
}

// fb[c] = sum_h wsoft[h] * b_gat[h*256+c]
__global__ void fb_kernel(const float* __restrict__ b_gat, const float* __restrict__ wsoft,
                          float* __restrict__ fb) {
  int c = threadIdx.x;
  float a = 0.f;
  #pragma unroll
  for (int h = 0; h < 8; ++h) a += wsoft[h] * b_gat[h * 256 + c];
  fb[c] = a;
}

extern "C" void kernel_launch(void* const* d_in, const int* in_sizes, int n_in,
                              void* d_out, int out_size, void* d_ws, size_t ws_size,
                              hipStream_t stream) {
  (void)in_sizes; (void)n_in; (void)out_size; (void)ws_size;
  const float* x      = (const float*)d_in[0];
  const int*   ei     = (const int*)d_in[1];
  const float* W_gat  = (const float*)d_in[2];
  const float* att_s  = (const float*)d_in[3];
  const float* att_d  = (const float*)d_in[4];
  const float* b_gat  = (const float*)d_in[5];
  const float* conv_w = (const float*)d_in[6];
  const float* conv_b = (const float*)d_in[7];
  const float* W_lin  = (const float*)d_in[8];
  const float* b_lin  = (const float*)d_in[9];
  float* out = (float*)d_out;

  char* p = (char*)d_ws;
  size_t off = 0;
  auto alloc = [&](size_t bytes) -> void* {
    void* r = p + off;
    off = (off + bytes + 255) & ~(size_t)255;
    return r;
  };
  short* x_bf   = (short*)alloc((size_t)20000 * 256 * 2);  // reused as Hf after alphaz
  short* wmixT  = (short*)alloc((size_t)256 * 2048 * 2);
  short* wlT    = (short*)alloc((size_t)256 * 256 * 2);
  float* ws_s   = (float*)alloc(2048 * 4);
  float* ws_d   = (float*)alloc(2048 * 4);
  float* ws_r   = (float*)alloc(2048 * 4);
  float* a_s    = (float*)alloc((size_t)20000 * 8 * 4);
  float* a_d    = (float*)alloc((size_t)20000 * 8 * 4);
  float* rs     = (float*)alloc((size_t)20000 * 8 * 4);
  int*   deg    = (int*)alloc(20000 * 4);
  float* pooled = (float*)alloc(8 * 4);
  float* wsoft  = (float*)alloc(8 * 4);
  float* fb     = (float*)alloc(256 * 4);
  int*   rowptr = (int*)alloc(20001 * 4);
  int*   cursor = (int*)alloc(20000 * 4);
  int*   csr    = (int*)alloc(200000 * 4);
  float* pp     = (float*)alloc((size_t)20000 * 8 * 4);
  short* u      = (short*)alloc((size_t)20000 * 2048 * 2);
  short* Hf     = x_bf;  // x_bf dead after alphaz; Hf written by gemm<2>

  hipMemsetAsync(deg, 0, 20000 * 4, stream);
  hipMemsetAsync(pooled, 0, 8 * 4, stream);

  transpose_kernel<<<dim3(8, 8), dim3(32, 8), 0, stream>>>(W_lin, wlT, 256, 250, 256);
  prepws_kernel<<<8, 256, 0, stream>>>(W_gat, att_s, att_d, ws_s, ws_d, ws_r);
  asd_kernel<<<625, 256, 0, stream>>>(x, ws_s, ws_d, ws_r, a_s, a_d, rs, x_bf);
  hist_kernel<<<782, 256, 0, stream>>>(ei, deg, 200000);
  scan_kernel<<<1, 1024, 0, stream>>>(deg, rowptr, cursor, 20000);
  scatter_kernel<<<782, 256, 0, stream>>>(ei, cursor, csr, 200000);
  alphaz_kernel<<<5000, 256, 0, stream>>>(x_bf, a_s, a_d, rs, rowptr, csr, u, pp);
  reduce_pp_kernel<<<80, 256, 0, stream>>>(pp, pooled);
  headw_kernel<<<1, 256, 0, stream>>>(pooled, b_gat, conv_w, conv_b, wsoft);
  wmix_kernel<<<dim3(8, 8, 8), dim3(32, 8), 0, stream>>>(W_gat, wsoft, wmixT);
  fb_kernel<<<1, 256, 0, stream>>>(b_gat, wsoft, fb);
  // Hf = relu(u @ Wmix + fb + x)  [20000x256 bf16], BK=128, 16 K-steps
  gemm_kernel<2><<<313, 256, 0, stream>>>(u, wmixT, 20000, 2048,
                                          Hf, nullptr, fb, x, 256);
  // out = Hf @ W_lin + b_lin  [20000x250 f32], BK=128, 2 K-steps
  gemm_kernel<1><<<313, 256, 0, stream>>>(Hf, wlT, 20000, 256,
                                          nullptr, out, b_lin, nullptr, 250);
}

// Round 8
// 236.298 us; speedup vs baseline: 1.1737x; 1.1737x over previous
//
#include <hip/hip_runtime.h>
#include <hip/hip_bf16.h>

// N=20000 nodes, E=200000 edges, H=8, C=256, IN=256, OUT=250, H*C=2048.
// R8: single-pass alphaz — no-max softmax (logits bounded, f32-safe; identical math),
//     normalization deferred (linear), lane-parallel exp + v_readlane broadcast
//     (8 exp/edge total instead of 512). GEMMs unchanged from R7 (BK=128).

typedef __attribute__((ext_vector_type(8))) short short8v;
typedef __attribute__((ext_vector_type(4))) float float4v;

__device__ __forceinline__ unsigned f2bfu(float f) {
  unsigned u = __float_as_uint(f);
  return (u + 0x7fffu + ((u >> 16) & 1u)) >> 16;  // RNE f32 -> bf16
}
__device__ __forceinline__ float bfu_lo(unsigned u) { return __uint_as_float(u << 16); }
__device__ __forceinline__ float bfu_hi(unsigned u) { return __uint_as_float(u & 0xffff0000u); }
__device__ __forceinline__ unsigned pack2(float a, float b) { return f2bfu(a) | (f2bfu(b) << 16); }

__device__ __forceinline__ void ld8(const float* p, float* v) {
  float4 a = ((const float4*)p)[0], b = ((const float4*)p)[1];
  v[0] = a.x; v[1] = a.y; v[2] = a.z; v[3] = a.w;
  v[4] = b.x; v[5] = b.y; v[6] = b.z; v[7] = b.w;
}
__device__ __forceinline__ void st8(float* p, const float* v) {
  ((float4*)p)[0] = make_float4(v[0], v[1], v[2], v[3]);
  ((float4*)p)[1] = make_float4(v[4], v[5], v[6], v[7]);
}

__device__ __forceinline__ float bcast(float x, int e) {
  return __uint_as_float((unsigned)__builtin_amdgcn_readlane((int)__float_as_uint(x), e));
}

__device__ __forceinline__ void gll16(const void* g, void* l) {
  __builtin_amdgcn_global_load_lds(
      (__attribute__((address_space(1))) void*)const_cast<void*>(g),
      (__attribute__((address_space(3))) void*)(l), 16, 0, 0);
}

// ---------------- small prep kernels ----------------

// out[c][r] = bf16(in[r][c]); zero-pads columns c in [Cc, Cpad)
__global__ void transpose_kernel(const float* __restrict__ in, short* __restrict__ out,
                                 int R, int Cc, int Cpad) {
  __shared__ float tile[32][33];
  int tx = threadIdx.x, ty = threadIdx.y;
  int c0 = blockIdx.x * 32, r0 = blockIdx.y * 32;
  #pragma unroll
  for (int j = ty; j < 32; j += 8) {
    int r = r0 + j, c = c0 + tx;
    tile[j][tx] = (r < R && c < Cc) ? in[(size_t)r * Cc + c] : 0.f;
  }
  __syncthreads();
  #pragma unroll
  for (int j = ty; j < 32; j += 8) {
    int c = c0 + j, r = r0 + tx;
    if (c < Cpad && r < R) out[(size_t)c * R + r] = (short)f2bfu(tile[tx][j]);
  }
}

// wmixT[c][h*256+k] = bf16(wsoft[h] * W_gat[k][h*256+c])  (scaled per-head transpose)
__global__ void wmix_kernel(const float* __restrict__ W, const float* __restrict__ wsoft,
                            short* __restrict__ out) {
  __shared__ float tile[32][33];
  int tx = threadIdx.x, ty = threadIdx.y;
  int h = blockIdx.z;
  float wh = wsoft[h];
  int c0 = blockIdx.x * 32, k0 = blockIdx.y * 32;
  #pragma unroll
  for (int j = ty; j < 32; j += 8)
    tile[j][tx] = W[(size_t)(k0 + j) * 2048 + h * 256 + c0 + tx];
  __syncthreads();
  #pragma unroll
  for (int j = ty; j < 32; j += 8)
    out[(size_t)(c0 + j) * 2048 + h * 256 + k0 + tx] = (short)f2bfu(wh * tile[tx][j]);
}

// ws_s[k*8+h] = sum_c W[k][h*256+c]*att_src[h][c]; ws_r = plain row-chunk sum
__global__ void prepws_kernel(const float* __restrict__ W, const float* __restrict__ att_s,
                              const float* __restrict__ att_d, float* __restrict__ ws_s,
                              float* __restrict__ ws_d, float* __restrict__ ws_r) {
  int g = blockIdx.x * 256 + threadIdx.x;  // 0..2047
  int k = g >> 3, h = g & 7;
  const float* wr = W + (size_t)k * 2048 + h * 256;
  const float* as = att_s + h * 256;
  const float* ad = att_d + h * 256;
  float s = 0.f, dd = 0.f, r = 0.f;
  for (int c = 0; c < 256; ++c) {
    float wv = wr[c];
    s += wv * as[c];
    dd += wv * ad[c];
    r += wv;
  }
  ws_s[g] = s;
  ws_d[g] = dd;
  ws_r[g] = r;
}

// a_s/a_d/rs[n][h] = x[n,:] . ws_*[:,h] (f32 exact); also emits x_bf (bf16 of x)
__global__ __launch_bounds__(256) void asd_kernel(const float* __restrict__ x,
    const float* __restrict__ ws_s, const float* __restrict__ ws_d,
    const float* __restrict__ ws_r, float* __restrict__ a_s,
    float* __restrict__ a_d, float* __restrict__ rs, short* __restrict__ x_bf) {
  __shared__ float ls[2048], ld2[2048], lr[2048];
  int tid = threadIdx.x;
  for (int i = tid; i < 2048; i += 256) { ls[i] = ws_s[i]; ld2[i] = ws_d[i]; lr[i] = ws_r[i]; }
  __syncthreads();
  int node = blockIdx.x * 32 + (tid >> 3);
  int h = tid & 7;
  const float4* xr = (const float4*)(x + (size_t)node * 256);
  float as = 0.f, ad = 0.f, rr = 0.f;
  for (int k4 = 0; k4 < 64; ++k4) {
    float4 v = xr[k4];
    int k8 = k4 * 32 + h;
    as += v.x * ls[k8] + v.y * ls[k8 + 8] + v.z * ls[k8 + 16] + v.w * ls[k8 + 24];
    ad += v.x * ld2[k8] + v.y * ld2[k8 + 8] + v.z * ld2[k8 + 16] + v.w * ld2[k8 + 24];
    rr += v.x * lr[k8] + v.y * lr[k8 + 8] + v.z * lr[k8 + 16] + v.w * lr[k8 + 24];
    if ((k4 & 7) == h) {  // this thread owns the bf16 write of chunk k4
      uint2 ov;
      ov.x = pack2(v.x, v.y);
      ov.y = pack2(v.z, v.w);
      *(uint2*)(x_bf + (size_t)node * 256 + k4 * 4) = ov;
    }
  }
  a_s[node * 8 + h] = as;
  a_d[node * 8 + h] = ad;
  rs[node * 8 + h] = rr;
}

// ---------------- bf16 MFMA GEMM (64x256 tile, BK=128, 4 waves) ----------------
// C[M][256] = A[M][K] * BT[256][K]^T ; wave w owns output cols w*64..w*64+63.
// LDS [row][128] shorts, row stride 256B; chunk XOR (row&7) balances b128 reads.
// EPI=1: f32 store + bias, col<Nout.  EPI=2: bf16 store of relu(acc+bias+xres).
template <int EPI>
__global__ __launch_bounds__(256, 2) void gemm_kernel(
    const short* __restrict__ A, const short* __restrict__ BT,
    int M, int K,
    short* __restrict__ Cb, float* __restrict__ Cf,
    const float* __restrict__ bias, const float* __restrict__ xres, int Nout) {
  __shared__ short lA[64 * 128];    // 16 KB
  __shared__ short lB[256 * 128];   // 64 KB
  int tid = threadIdx.x;
  int wave = tid >> 6, lane = tid & 63;
  int m0 = blockIdx.x << 6;
  int lr = lane & 15, lq = lane >> 4;
  int lrow4 = lane >> 4;            // 0..3 row-within-stage
  int pch = lane & 15;              // physical 16B chunk within row

  float4v acc[4][4];
  #pragma unroll
  for (int i = 0; i < 4; ++i)
    #pragma unroll
    for (int j = 0; j < 4; ++j) acc[i][j] = (float4v){0.f, 0.f, 0.f, 0.f};

  // per-lane global element offsets for staging (invariant part)
  int offA[4];
  #pragma unroll
  for (int it = 0; it < 4; ++it) {
    int rowl = wave * 16 + it * 4 + lrow4;          // local row 0..63
    int grow = m0 + rowl;
    if (grow >= M) grow = M - 1;                    // clamp; masked at store
    int logical = pch ^ (rowl & 7);
    offA[it] = grow * K + logical * 8;
  }
  int offB[16];
  #pragma unroll
  for (int it = 0; it < 16; ++it) {
    int rowb = wave * 64 + it * 4 + lrow4;          // 0..255 (col of C)
    int logical = pch ^ (rowb & 7);
    offB[it] = rowb * K + logical * 8;
  }

  int nk = K >> 7;
  for (int t = 0; t < nk; ++t) {
    int k0 = t << 7;
    __syncthreads();
    #pragma unroll
    for (int it = 0; it < 4; ++it)
      gll16(A + offA[it] + k0, lA + (wave * 16 + it * 4) * 128);
    #pragma unroll
    for (int it = 0; it < 16; ++it)
      gll16(BT + offB[it] + k0, lB + (wave * 64 + it * 4) * 128);
    __syncthreads();
    #pragma unroll
    for (int ks = 0; ks < 4; ++ks) {
      int phys = ((ks * 4 + lq) ^ (lr & 7)) * 8;
      short8v af[4], bfv[4];
      #pragma unroll
      for (int i = 0; i < 4; ++i)
        af[i] = *(const short8v*)(lA + (i * 16 + lr) * 128 + phys);
      #pragma unroll
      for (int j = 0; j < 4; ++j)
        bfv[j] = *(const short8v*)(lB + (wave * 64 + j * 16 + lr) * 128 + phys);
      #pragma unroll
      for (int i = 0; i < 4; ++i)
        #pragma unroll
        for (int j = 0; j < 4; ++j)
          acc[i][j] = __builtin_amdgcn_mfma_f32_16x16x32_bf16(af[i], bfv[j], acc[i][j], 0, 0, 0);
    }
  }

  #pragma unroll
  for (int i = 0; i < 4; ++i) {
    #pragma unroll
    for (int jj = 0; jj < 4; ++jj) {
      int row = m0 + i * 16 + lq * 4 + jj;  // C/D: row=(l>>4)*4+reg, col=l&15
      if (row >= M) continue;
      #pragma unroll
      for (int j = 0; j < 4; ++j) {
        int col = wave * 64 + j * 16 + lr;
        float v = acc[i][j][jj];
        if (EPI == 1) {
          if (col < Nout) Cf[(size_t)row * Nout + col] = v + bias[col];
        } else {
          float o = v + bias[col] + xres[(size_t)row * 256 + col];
          Cb[(size_t)row * 256 + col] = (short)f2bfu(fmaxf(o, 0.f));
        }
      }
    }
  }
}

// ---------------- CSR build ----------------

__global__ void hist_kernel(const int* __restrict__ ei, int* __restrict__ deg, int E) {
  int e = blockIdx.x * 256 + threadIdx.x;
  if (e < E) atomicAdd(&deg[ei[E + e]], 1);
}

// single block, 1024 threads, 20 elems/thread local scan + one 1024-wide scan
__global__ __launch_bounds__(1024) void scan_kernel(const int* __restrict__ deg,
                                                    int* __restrict__ rowptr,
                                                    int* __restrict__ cursor, int n) {
  __shared__ int part[1024];
  int t = threadIdx.x;
  int base = t * 20;
  int loc[20];
  int run = 0;
  #pragma unroll
  for (int j = 0; j < 20; ++j) {
    int idx = base + j;
    int v = (idx < n) ? deg[idx] : 0;
    loc[j] = run;
    run += v;
  }
  part[t] = run;
  __syncthreads();
  for (int off = 1; off < 1024; off <<= 1) {
    int add = (t >= off) ? part[t - off] : 0;
    __syncthreads();
    part[t] += add;
    __syncthreads();
  }
  int off0 = (t > 0) ? part[t - 1] : 0;
  #pragma unroll
  for (int j = 0; j < 20; ++j) {
    int idx = base + j;
    if (idx < n) {
      int v = off0 + loc[j];
      rowptr[idx] = v;
      cursor[idx] = v;
    }
  }
  if (t == 1023) rowptr[n] = part[1023];
}

__global__ void scatter_kernel(const int* __restrict__ ei, int* __restrict__ cursor,
                               int* __restrict__ csr_src, int E) {
  int e = blockIdx.x * 256 + threadIdx.x;
  if (e < E) {
    int pos = atomicAdd(&cursor[ei[E + e]], 1);
    csr_src[pos] = ei[e];
  }
}

// ---------------- fused softmax + z-aggregate, single pass (wave per dst) ----------------
// No-max softmax (logits bounded; identical math), normalization deferred to epilogue.
// u[d][h*256+k] = (1/s_h) * sum_e ex_eh x_bf[src][k]   (wsoft folded into wmixT later)
// pp[d][h]      = (1/s_h) * sum_e ex_eh rs[src][h]
__global__ __launch_bounds__(256) void alphaz_kernel(
    const short* __restrict__ x_bf, const float* __restrict__ a_s,
    const float* __restrict__ a_d, const float* __restrict__ rs,
    const int* __restrict__ rowptr, const int* __restrict__ csr,
    short* __restrict__ u, float* __restrict__ pp) {
  int d = (blockIdx.x * 256 + threadIdx.x) >> 6;
  int lane = threadIdx.x & 63;
  int beg = rowptr[d];
  int deg = rowptr[d + 1] - beg;

  float ad[8];
  ld8(a_d + (size_t)d * 8, ad);

  float acc[8][4];
  #pragma unroll
  for (int h = 0; h < 8; ++h)
    #pragma unroll
    for (int j = 0; j < 4; ++j) acc[h][j] = 0.f;
  float s8l[8], p8l[8];

  // self edge (every lane adds its own channels; s/p only on lane 0 to avoid 64x)
  {
    float t[8], rsv[8];
    ld8(a_s + (size_t)d * 8, t);
    ld8(rs + (size_t)d * 8, rsv);
    uint2 v = *(const uint2*)(x_bf + (size_t)d * 256 + lane * 4);
    float xv0 = bfu_lo(v.x), xv1 = bfu_hi(v.x), xv2 = bfu_lo(v.y), xv3 = bfu_hi(v.y);
    float lz = (lane == 0) ? 1.f : 0.f;
    #pragma unroll
    for (int h = 0; h < 8; ++h) {
      float e = t[h] + ad[h];
      e = (e > 0.f) ? e : 0.2f * e;
      float ex = __expf(e);
      acc[h][0] += ex * xv0;
      acc[h][1] += ex * xv1;
      acc[h][2] += ex * xv2;
      acc[h][3] += ex * xv3;
      s8l[h] = ex * lz;
      p8l[h] = ex * rsv[h] * lz;
    }
  }

  for (int base = 0; base < deg; base += 64) {
    int i = base + lane;
    bool act = i < deg;
    int src = act ? csr[beg + i] : 0;
    // lane-parallel: 8 exps for THIS lane's edge only
    float ex[8];
    {
      float t[8], rsv[8];
      ld8(a_s + (size_t)src * 8, t);
      ld8(rs + (size_t)src * 8, rsv);
      #pragma unroll
      for (int h = 0; h < 8; ++h) {
        float e = t[h] + ad[h];
        e = (e > 0.f) ? e : 0.2f * e;
        float xx = __expf(e);
        ex[h] = act ? xx : 0.f;
        s8l[h] += ex[h];
        p8l[h] += ex[h] * rsv[h];
      }
    }
    // wave-serial accumulate: broadcast via v_readlane (SGPR scalar operand)
    int cnt = deg - base;
    if (cnt > 64) cnt = 64;
    for (int e = 0; e < cnt; ++e) {
      int srcb = __builtin_amdgcn_readlane(src, e);
      float q[8];
      #pragma unroll
      for (int h = 0; h < 8; ++h) q[h] = bcast(ex[h], e);
      uint2 v = *(const uint2*)(x_bf + (size_t)srcb * 256 + lane * 4);
      float xv0 = bfu_lo(v.x), xv1 = bfu_hi(v.x), xv2 = bfu_lo(v.y), xv3 = bfu_hi(v.y);
      #pragma unroll
      for (int h = 0; h < 8; ++h) {
        acc[h][0] += q[h] * xv0;
        acc[h][1] += q[h] * xv1;
        acc[h][2] += q[h] * xv2;
        acc[h][3] += q[h] * xv3;
      }
    }
  }

  // reduce s/p across lanes, normalize, write out
  #pragma unroll
  for (int off = 1; off < 64; off <<= 1)
    #pragma unroll
    for (int h = 0; h < 8; ++h) {
      s8l[h] += __shfl_xor(s8l[h], off);
      p8l[h] += __shfl_xor(p8l[h], off);
    }
  float inv[8];
  #pragma unroll
  for (int h = 0; h < 8; ++h) inv[h] = 1.f / (s8l[h] + 1e-16f);
  #pragma unroll
  for (int h = 0; h < 8; ++h) {
    uint2 ov;
    ov.x = pack2(acc[h][0] * inv[h], acc[h][1] * inv[h]);
    ov.y = pack2(acc[h][2] * inv[h], acc[h][3] * inv[h]);
    *(uint2*)(u + (size_t)d * 2048 + h * 256 + lane * 4) = ov;
  }
  if (lane == 0) {
    float pn[8];
    #pragma unroll
    for (int h = 0; h < 8; ++h) pn[h] = p8l[h] * inv[h];
    st8(pp + (size_t)d * 8, pn);
  }
}

// ---------------- pooled reduction ----------------
__global__ __launch_bounds__(256) void reduce_pp_kernel(const float* __restrict__ pp,
                                                        float* __restrict__ pooled) {
  int tid = threadIdx.x;
  float loc[8] = {0, 0, 0, 0, 0, 0, 0, 0};
  for (int r = blockIdx.x * 256 + tid; r < 20000; r += 80 * 256) {
    float t[8];
    ld8(pp + (size_t)r * 8, t);
    #pragma unroll
    for (int h = 0; h < 8; ++h) loc[h] += t[h];
  }
  #pragma unroll
  for (int off = 1; off < 64; off <<= 1)
    #pragma unroll
    for (int h = 0; h < 8; ++h) loc[h] += __shfl_xor(loc[h], off);
  __shared__ float sred[4][8];
  int wave = tid >> 6, lane = tid & 63;
  if (lane == 0) {
    #pragma unroll
    for (int h = 0; h < 8; ++h) sred[wave][h] = loc[h];
  }
  __syncthreads();
  if (tid < 8) {
    atomicAdd(&pooled[tid], sred[0][tid] + sred[1][tid] + sred[2][tid] + sred[3][tid]);
  }
}

// ---------------- head softmax weights ----------------
__global__ __launch_bounds__(256) void headw_kernel(const float* __restrict__ pooled,
    const float* __restrict__ b_gat, const float* __restrict__ conv_w,
    const float* __restrict__ conv_b, float* __restrict__ wsoft) {
  __shared__ float sb[8];
  int t = threadIdx.x;
  float v = 0.f;
  #pragma unroll
  for (int j = 0; j < 8; ++j) v += b_gat[t * 8 + j];
  #pragma unroll
  for (int off = 1; off < 32; off <<= 1) v += __shfl_xor(v, off);
  if ((t & 31) == 0 && t < 256) sb[t >> 5] = v;
  __syncthreads();
  if (t == 0) {
    const float invNC = 1.0f / (20000.0f * 256.0f);
    float g[8];
    float mx = -1e30f;
    #pragma unroll
    for (int h = 0; h < 8; ++h) {
      float pm = (pooled[h] + 20000.0f * sb[h]) * invNC;
      float gv = pm * conv_w[0] + conv_b[0];
      gv = fmaxf(gv, 0.f);
      g[h] = gv;
      mx = fmaxf(mx, gv);
    }
    float ssum = 0.f;
    #pragma unroll
    for (int h = 0; h < 8; ++h) { g[h] = __expf(g[h] - mx); ssum += g[h]; }
    #pragma unroll
    for (int h = 0; h < 8; ++h) wsoft[h] = g[h] / ssum;
  }
}

// fb[c] = sum_h wsoft[h] * b_gat[h*256+c]
__global__ void fb_kernel(const float* __restrict__ b_gat, const float* __restrict__ wsoft,
                          float* __restrict__ fb) {
  int c = threadIdx.x;
  float a = 0.f;
  #pragma unroll
  for (int h = 0; h < 8; ++h) a += wsoft[h] * b_gat[h * 256 + c];
  fb[c] = a;
}

extern "C" void kernel_launch(void* const* d_in, const int* in_sizes, int n_in,
                              void* d_out, int out_size, void* d_ws, size_t ws_size,
                              hipStream_t stream) {
  (void)in_sizes; (void)n_in; (void)out_size; (void)ws_size;
  const float* x      = (const float*)d_in[0];
  const int*   ei     = (const int*)d_in[1];
  const float* W_gat  = (const float*)d_in[2];
  const float* att_s  = (const float*)d_in[3];
  const float* att_d  = (const float*)d_in[4];
  const float* b_gat  = (const float*)d_in[5];
  const float* conv_w = (const float*)d_in[6];
  const float* conv_b = (const float*)d_in[7];
  const float* W_lin  = (const float*)d_in[8];
  const float* b_lin  = (const float*)d_in[9];
  float* out = (float*)d_out;

  char* p = (char*)d_ws;
  size_t off = 0;
  auto alloc = [&](size_t bytes) -> void* {
    void* r = p + off;
    off = (off + bytes + 255) & ~(size_t)255;
    return r;
  };
  short* x_bf   = (short*)alloc((size_t)20000 * 256 * 2);  // reused as Hf after alphaz
  short* wmixT  = (short*)alloc((size_t)256 * 2048 * 2);
  short* wlT    = (short*)alloc((size_t)256 * 256 * 2);
  float* ws_s   = (float*)alloc(2048 * 4);
  float* ws_d   = (float*)alloc(2048 * 4);
  float* ws_r   = (float*)alloc(2048 * 4);
  float* a_s    = (float*)alloc((size_t)20000 * 8 * 4);
  float* a_d    = (float*)alloc((size_t)20000 * 8 * 4);
  float* rs     = (float*)alloc((size_t)20000 * 8 * 4);
  int*   deg    = (int*)alloc(20000 * 4);
  float* pooled = (float*)alloc(8 * 4);
  float* wsoft  = (float*)alloc(8 * 4);
  float* fb     = (float*)alloc(256 * 4);
  int*   rowptr = (int*)alloc(20001 * 4);
  int*   cursor = (int*)alloc(20000 * 4);
  int*   csr    = (int*)alloc(200000 * 4);
  float* pp     = (float*)alloc((size_t)20000 * 8 * 4);
  short* u      = (short*)alloc((size_t)20000 * 2048 * 2);
  short* Hf     = x_bf;  // x_bf dead after alphaz; Hf written by gemm<2>

  hipMemsetAsync(deg, 0, 20000 * 4, stream);
  hipMemsetAsync(pooled, 0, 8 * 4, stream);

  transpose_kernel<<<dim3(8, 8), dim3(32, 8), 0, stream>>>(W_lin, wlT, 256, 250, 256);
  prepws_kernel<<<8, 256, 0, stream>>>(W_gat, att_s, att_d, ws_s, ws_d, ws_r);
  asd_kernel<<<625, 256, 0, stream>>>(x, ws_s, ws_d, ws_r, a_s, a_d, rs, x_bf);
  hist_kernel<<<782, 256, 0, stream>>>(ei, deg, 200000);
  scan_kernel<<<1, 1024, 0, stream>>>(deg, rowptr, cursor, 20000);
  scatter_kernel<<<782, 256, 0, stream>>>(ei, cursor, csr, 200000);
  alphaz_kernel<<<5000, 256, 0, stream>>>(x_bf, a_s, a_d, rs, rowptr, csr, u, pp);
  reduce_pp_kernel<<<80, 256, 0, stream>>>(pp, pooled);
  headw_kernel<<<1, 256, 0, stream>>>(pooled, b_gat, conv_w, conv_b, wsoft);
  wmix_kernel<<<dim3(8, 8, 8), dim3(32, 8), 0, stream>>>(W_gat, wsoft, wmixT);
  fb_kernel<<<1, 256, 0, stream>>>(b_gat, wsoft, fb);
  // Hf = relu(u @ Wmix + fb + x)  [20000x256 bf16], BK=128, 16 K-steps
  gemm_kernel<2><<<313, 256, 0, stream>>>(u, wmixT, 20000, 2048,
                                          Hf, nullptr, fb, x, 256);
  // out = Hf @ W_lin + b_lin  [20000x250 f32], BK=128, 2 K-steps
  gemm_kernel<1><<<313, 256, 0, stream>>>(Hf, wlT, 20000, 256,
                                          nullptr, out, b_lin, nullptr, 250);
}

// Round 10
// 223.315 us; speedup vs baseline: 1.2419x; 1.0581x over previous
//
#include <hip/hip_runtime.h>
#include <hip/hip_bf16.h>

// N=20000 nodes, E=200000 edges, H=8, C=256, IN=256, OUT=250, H*C=2048.
// R10: R9 with fixes — prepws grid 32 (not 256; W_gat k-range is 0..255, the 256-block
//      launch read/wrote 8x OOB and faulted), and vn initialized in alphaz prefetch.

typedef __attribute__((ext_vector_type(8))) short short8v;
typedef __attribute__((ext_vector_type(4))) float float4v;

__device__ __forceinline__ unsigned f2bfu(float f) {
  unsigned u = __float_as_uint(f);
  return (u + 0x7fffu + ((u >> 16) & 1u)) >> 16;  // RNE f32 -> bf16
}
__device__ __forceinline__ float bfu_lo(unsigned u) { return __uint_as_float(u << 16); }
__device__ __forceinline__ float bfu_hi(unsigned u) { return __uint_as_float(u & 0xffff0000u); }
__device__ __forceinline__ unsigned pack2(float a, float b) { return f2bfu(a) | (f2bfu(b) << 16); }

__device__ __forceinline__ void ld8(const float* p, float* v) {
  float4 a = ((const float4*)p)[0], b = ((const float4*)p)[1];
  v[0] = a.x; v[1] = a.y; v[2] = a.z; v[3] = a.w;
  v[4] = b.x; v[5] = b.y; v[6] = b.z; v[7] = b.w;
}
__device__ __forceinline__ void ld4(const float* p, float* v) {
  float4 a = ((const float4*)p)[0];
  v[0] = a.x; v[1] = a.y; v[2] = a.z; v[3] = a.w;
}

__device__ __forceinline__ float bcast(float x, int e) {
  return __uint_as_float((unsigned)__builtin_amdgcn_readlane((int)__float_as_uint(x), e));
}

__device__ __forceinline__ void gll16(const void* g, void* l) {
  __builtin_amdgcn_global_load_lds(
      (__attribute__((address_space(1))) void*)const_cast<void*>(g),
      (__attribute__((address_space(3))) void*)(l), 16, 0, 0);
}

// ---------------- small prep kernels ----------------

// out[c][r] = bf16(in[r][c]); zero-pads columns c in [Cc, Cpad)
__global__ void transpose_kernel(const float* __restrict__ in, short* __restrict__ out,
                                 int R, int Cc, int Cpad) {
  __shared__ float tile[32][33];
  int tx = threadIdx.x, ty = threadIdx.y;
  int c0 = blockIdx.x * 32, r0 = blockIdx.y * 32;
  #pragma unroll
  for (int j = ty; j < 32; j += 8) {
    int r = r0 + j, c = c0 + tx;
    tile[j][tx] = (r < R && c < Cc) ? in[(size_t)r * Cc + c] : 0.f;
  }
  __syncthreads();
  #pragma unroll
  for (int j = ty; j < 32; j += 8) {
    int c = c0 + j, r = r0 + tx;
    if (c < Cpad && r < R) out[(size_t)c * R + r] = (short)f2bfu(tile[tx][j]);
  }
}

// wmixT[c][h*256+k] = bf16(wsoft[h] * W_gat[k][h*256+c])  (scaled per-head transpose)
__global__ void wmix_kernel(const float* __restrict__ W, const float* __restrict__ wsoft,
                            short* __restrict__ out) {
  __shared__ float tile[32][33];
  int tx = threadIdx.x, ty = threadIdx.y;
  int h = blockIdx.z;
  float wh = wsoft[h];
  int c0 = blockIdx.x * 32, k0 = blockIdx.y * 32;
  #pragma unroll
  for (int j = ty; j < 32; j += 8)
    tile[j][tx] = W[(size_t)(k0 + j) * 2048 + h * 256 + c0 + tx];
  __syncthreads();
  #pragma unroll
  for (int j = ty; j < 32; j += 8)
    out[(size_t)(c0 + j) * 2048 + h * 256 + k0 + tx] = (short)f2bfu(wh * tile[tx][j]);
}

// ws_s[k*8+h] = sum_c W[k][h*256+c]*att_src[h][c]; ws_r = plain row-chunk sum.
// 32 blocks; block b handles k in [b*8, b*8+8) (k range 0..255); (k,h) over 4 lanes x float4.
__global__ __launch_bounds__(256) void prepws_kernel(
    const float* __restrict__ W, const float* __restrict__ att_s,
    const float* __restrict__ att_d, float* __restrict__ ws_s,
    float* __restrict__ ws_d, float* __restrict__ ws_r) {
  __shared__ float sas[2048], sad[2048];
  int tid = threadIdx.x;
  for (int i = tid; i < 2048; i += 256) { sas[i] = att_s[i]; sad[i] = att_d[i]; }
  __syncthreads();
  int kk = tid >> 5, h = (tid >> 2) & 7, q = tid & 3;
  int k = blockIdx.x * 8 + kk;
  const float4* wr = (const float4*)(W + (size_t)k * 2048 + h * 256 + q * 64);
  const float* as = sas + h * 256 + q * 64;
  const float* ad = sad + h * 256 + q * 64;
  float s = 0.f, dd = 0.f, r = 0.f;
  #pragma unroll
  for (int c4 = 0; c4 < 16; ++c4) {
    float4 wv = wr[c4];
    int c = c4 * 4;
    s  += wv.x * as[c] + wv.y * as[c + 1] + wv.z * as[c + 2] + wv.w * as[c + 3];
    dd += wv.x * ad[c] + wv.y * ad[c + 1] + wv.z * ad[c + 2] + wv.w * ad[c + 3];
    r  += wv.x + wv.y + wv.z + wv.w;
  }
  #pragma unroll
  for (int off = 1; off < 4; off <<= 1) {
    s += __shfl_xor(s, off);
    dd += __shfl_xor(dd, off);
    r += __shfl_xor(r, off);
  }
  if (q == 0) {
    int g = k * 8 + h;
    ws_s[g] = s;
    ws_d[g] = dd;
    ws_r[g] = r;
  }
}

// a_s/a_d/rs[n][h] = x[n,:] . ws_*[:,h] (f32 exact); also emits x_bf (bf16 of x)
__global__ __launch_bounds__(256) void asd_kernel(const float* __restrict__ x,
    const float* __restrict__ ws_s, const float* __restrict__ ws_d,
    const float* __restrict__ ws_r, float* __restrict__ a_s,
    float* __restrict__ a_d, float* __restrict__ rs, short* __restrict__ x_bf) {
  __shared__ float ls[2048], ld2[2048], lr[2048];
  int tid = threadIdx.x;
  for (int i = tid; i < 2048; i += 256) { ls[i] = ws_s[i]; ld2[i] = ws_d[i]; lr[i] = ws_r[i]; }
  __syncthreads();
  int node = blockIdx.x * 32 + (tid >> 3);
  int h = tid & 7;
  const float4* xr = (const float4*)(x + (size_t)node * 256);
  float as = 0.f, ad = 0.f, rr = 0.f;
  for (int k4 = 0; k4 < 64; ++k4) {
    float4 v = xr[k4];
    int k8 = k4 * 32 + h;
    as += v.x * ls[k8] + v.y * ls[k8 + 8] + v.z * ls[k8 + 16] + v.w * ls[k8 + 24];
    ad += v.x * ld2[k8] + v.y * ld2[k8 + 8] + v.z * ld2[k8 + 16] + v.w * ld2[k8 + 24];
    rr += v.x * lr[k8] + v.y * lr[k8 + 8] + v.z * lr[k8 + 16] + v.w * lr[k8 + 24];
    if ((k4 & 7) == h) {  // this thread owns the bf16 write of chunk k4
      uint2 ov;
      ov.x = pack2(v.x, v.y);
      ov.y = pack2(v.z, v.w);
      *(uint2*)(x_bf + (size_t)node * 256 + k4 * 4) = ov;
    }
  }
  a_s[node * 8 + h] = as;
  a_d[node * 8 + h] = ad;
  rs[node * 8 + h] = rr;
}

// ---------------- bf16 MFMA GEMM (64x256 tile, BK=128, 4 waves) ----------------
// C[M][256] = A[M][K] * BT[256][K]^T ; wave w owns output cols w*64..w*64+63.
// LDS [row][128] shorts, row stride 256B; chunk XOR (row&7) balances b128 reads.
// EPI=1: f32 store + bias, col<Nout.  EPI=2: bf16 store of relu(acc+bias+xres).
template <int EPI>
__global__ __launch_bounds__(256, 2) void gemm_kernel(
    const short* __restrict__ A, const short* __restrict__ BT,
    int M, int K,
    short* __restrict__ Cb, float* __restrict__ Cf,
    const float* __restrict__ bias, const float* __restrict__ xres, int Nout) {
  __shared__ short lA[64 * 128];    // 16 KB
  __shared__ short lB[256 * 128];   // 64 KB
  int tid = threadIdx.x;
  int wave = tid >> 6, lane = tid & 63;
  int m0 = blockIdx.x << 6;
  int lr = lane & 15, lq = lane >> 4;
  int lrow4 = lane >> 4;            // 0..3 row-within-stage
  int pch = lane & 15;              // physical 16B chunk within row

  float4v acc[4][4];
  #pragma unroll
  for (int i = 0; i < 4; ++i)
    #pragma unroll
    for (int j = 0; j < 4; ++j) acc[i][j] = (float4v){0.f, 0.f, 0.f, 0.f};

  // per-lane global element offsets for staging (invariant part)
  int offA[4];
  #pragma unroll
  for (int it = 0; it < 4; ++it) {
    int rowl = wave * 16 + it * 4 + lrow4;          // local row 0..63
    int grow = m0 + rowl;
    if (grow >= M) grow = M - 1;                    // clamp; masked at store
    int logical = pch ^ (rowl & 7);
    offA[it] = grow * K + logical * 8;
  }
  int offB[16];
  #pragma unroll
  for (int it = 0; it < 16; ++it) {
    int rowb = wave * 64 + it * 4 + lrow4;          // 0..255 (col of C)
    int logical = pch ^ (rowb & 7);
    offB[it] = rowb * K + logical * 8;
  }

  int nk = K >> 7;
  for (int t = 0; t < nk; ++t) {
    int k0 = t << 7;
    __syncthreads();
    #pragma unroll
    for (int it = 0; it < 4; ++it)
      gll16(A + offA[it] + k0, lA + (wave * 16 + it * 4) * 128);
    #pragma unroll
    for (int it = 0; it < 16; ++it)
      gll16(BT + offB[it] + k0, lB + (wave * 64 + it * 4) * 128);
    __syncthreads();
    #pragma unroll
    for (int ks = 0; ks < 4; ++ks) {
      int phys = ((ks * 4 + lq) ^ (lr & 7)) * 8;
      short8v af[4], bfv[4];
      #pragma unroll
      for (int i = 0; i < 4; ++i)
        af[i] = *(const short8v*)(lA + (i * 16 + lr) * 128 + phys);
      #pragma unroll
      for (int j = 0; j < 4; ++j)
        bfv[j] = *(const short8v*)(lB + (wave * 64 + j * 16 + lr) * 128 + phys);
      #pragma unroll
      for (int i = 0; i < 4; ++i)
        #pragma unroll
        for (int j = 0; j < 4; ++j)
          acc[i][j] = __builtin_amdgcn_mfma_f32_16x16x32_bf16(af[i], bfv[j], acc[i][j], 0, 0, 0);
    }
  }

  #pragma unroll
  for (int i = 0; i < 4; ++i) {
    #pragma unroll
    for (int jj = 0; jj < 4; ++jj) {
      int row = m0 + i * 16 + lq * 4 + jj;  // C/D: row=(l>>4)*4+reg, col=l&15
      if (row >= M) continue;
      #pragma unroll
      for (int j = 0; j < 4; ++j) {
        int col = wave * 64 + j * 16 + lr;
        float v = acc[i][j][jj];
        if (EPI == 1) {
          if (col < Nout) Cf[(size_t)row * Nout + col] = v + bias[col];
        } else {
          float o = v + bias[col] + xres[(size_t)row * 256 + col];
          Cb[(size_t)row * 256 + col] = (short)f2bfu(fmaxf(o, 0.f));
        }
      }
    }
  }
}

// ---------------- CSR build ----------------

__global__ void hist_kernel(const int* __restrict__ ei, int* __restrict__ deg, int E) {
  int e = blockIdx.x * 256 + threadIdx.x;
  if (e < E) atomicAdd(&deg[ei[E + e]], 1);
}

// single block, 1024 threads, 20 elems/thread local scan + one 1024-wide scan
__global__ __launch_bounds__(1024) void scan_kernel(const int* __restrict__ deg,
                                                    int* __restrict__ rowptr,
                                                    int* __restrict__ cursor, int n) {
  __shared__ int part[1024];
  int t = threadIdx.x;
  int base = t * 20;
  int loc[20];
  int run = 0;
  #pragma unroll
  for (int j = 0; j < 20; ++j) {
    int idx = base + j;
    int v = (idx < n) ? deg[idx] : 0;
    loc[j] = run;
    run += v;
  }
  part[t] = run;
  __syncthreads();
  for (int off = 1; off < 1024; off <<= 1) {
    int add = (t >= off) ? part[t - off] : 0;
    __syncthreads();
    part[t] += add;
    __syncthreads();
  }
  int off0 = (t > 0) ? part[t - 1] : 0;
  #pragma unroll
  for (int j = 0; j < 20; ++j) {
    int idx = base + j;
    if (idx < n) {
      int v = off0 + loc[j];
      rowptr[idx] = v;
      cursor[idx] = v;
    }
  }
  if (t == 1023) rowptr[n] = part[1023];
}

__global__ void scatter_kernel(const int* __restrict__ ei, int* __restrict__ cursor,
                               int* __restrict__ csr_src, int E) {
  int e = blockIdx.x * 256 + threadIdx.x;
  if (e < E) {
    int pos = atomicAdd(&cursor[ei[E + e]], 1);
    csr_src[pos] = ei[e];
  }
}

// ---------------- fused softmax + z-aggregate, single pass ----------------
// 2 waves per dst; wave handles 4 heads. No-max softmax, deferred normalization.
__global__ __launch_bounds__(256) void alphaz_kernel(
    const short* __restrict__ x_bf, const float* __restrict__ a_s,
    const float* __restrict__ a_d, const float* __restrict__ rs,
    const int* __restrict__ rowptr, const int* __restrict__ csr,
    short* __restrict__ u, float* __restrict__ pp) {
  int gw = blockIdx.x * 4 + (threadIdx.x >> 6);
  int d = gw >> 1;
  int wh = (gw & 1) * 4;          // head offset for this wave
  int lane = threadIdx.x & 63;
  int beg = rowptr[d];
  int deg = rowptr[d + 1] - beg;

  float ad[4];
  ld4(a_d + (size_t)d * 8 + wh, ad);

  float acc[4][4];
  #pragma unroll
  for (int h = 0; h < 4; ++h)
    #pragma unroll
    for (int j = 0; j < 4; ++j) acc[h][j] = 0.f;
  float s4[4], p4[4];

  // self edge
  {
    float t[4], rsv[4];
    ld4(a_s + (size_t)d * 8 + wh, t);
    ld4(rs + (size_t)d * 8 + wh, rsv);
    uint2 v = *(const uint2*)(x_bf + (size_t)d * 256 + lane * 4);
    float xv0 = bfu_lo(v.x), xv1 = bfu_hi(v.x), xv2 = bfu_lo(v.y), xv3 = bfu_hi(v.y);
    float lz = (lane == 0) ? 1.f : 0.f;
    #pragma unroll
    for (int h = 0; h < 4; ++h) {
      float e = t[h] + ad[h];
      e = (e > 0.f) ? e : 0.2f * e;
      float ex = __expf(e);
      acc[h][0] += ex * xv0;
      acc[h][1] += ex * xv1;
      acc[h][2] += ex * xv2;
      acc[h][3] += ex * xv3;
      s4[h] = ex * lz;
      p4[h] = ex * rsv[h] * lz;
    }
  }

  for (int base = 0; base < deg; base += 64) {
    int i = base + lane;
    bool act = i < deg;
    int src = act ? csr[beg + i] : 0;
    // lane-parallel: 4 exps for THIS lane's edge only
    float ex[4];
    {
      float t[4], rsv[4];
      ld4(a_s + (size_t)src * 8 + wh, t);
      ld4(rs + (size_t)src * 8 + wh, rsv);
      #pragma unroll
      for (int h = 0; h < 4; ++h) {
        float e = t[h] + ad[h];
        e = (e > 0.f) ? e : 0.2f * e;
        float xx = __expf(e);
        ex[h] = act ? xx : 0.f;
        s4[h] += ex[h];
        p4[h] += ex[h] * rsv[h];
      }
    }
    // wave-serial accumulate with 1-deep prefetch; broadcast via v_readlane
    int cnt = deg - base;
    if (cnt > 64) cnt = 64;
    int srcb = __builtin_amdgcn_readlane(src, 0);
    uint2 vc = *(const uint2*)(x_bf + (size_t)srcb * 256 + lane * 4);
    for (int e = 0; e < cnt; ++e) {
      uint2 vn = vc;
      if (e + 1 < cnt) {
        int srcn = __builtin_amdgcn_readlane(src, e + 1);
        vn = *(const uint2*)(x_bf + (size_t)srcn * 256 + lane * 4);
      }
      float q[4];
      #pragma unroll
      for (int h = 0; h < 4; ++h) q[h] = bcast(ex[h], e);
      float xv0 = bfu_lo(vc.x), xv1 = bfu_hi(vc.x), xv2 = bfu_lo(vc.y), xv3 = bfu_hi(vc.y);
      #pragma unroll
      for (int h = 0; h < 4; ++h) {
        acc[h][0] += q[h] * xv0;
        acc[h][1] += q[h] * xv1;
        acc[h][2] += q[h] * xv2;
        acc[h][3] += q[h] * xv3;
      }
      vc = vn;
    }
  }

  // reduce s/p across lanes, normalize, write out
  #pragma unroll
  for (int off = 1; off < 64; off <<= 1)
    #pragma unroll
    for (int h = 0; h < 4; ++h) {
      s4[h] += __shfl_xor(s4[h], off);
      p4[h] += __shfl_xor(p4[h], off);
    }
  float inv[4];
  #pragma unroll
  for (int h = 0; h < 4; ++h) inv[h] = 1.f / (s4[h] + 1e-16f);
  #pragma unroll
  for (int h = 0; h < 4; ++h) {
    uint2 ov;
    ov.x = pack2(acc[h][0] * inv[h], acc[h][1] * inv[h]);
    ov.y = pack2(acc[h][2] * inv[h], acc[h][3] * inv[h]);
    *(uint2*)(u + (size_t)d * 2048 + (wh + h) * 256 + lane * 4) = ov;
  }
  if (lane == 0) {
    float4 pn;
    pn.x = p4[0] * inv[0];
    pn.y = p4[1] * inv[1];
    pn.z = p4[2] * inv[2];
    pn.w = p4[3] * inv[3];
    *(float4*)(pp + (size_t)d * 8 + wh) = pn;
  }
}

// ---------------- pooled reduction ----------------
__global__ __launch_bounds__(256) void reduce_pp_kernel(const float* __restrict__ pp,
                                                        float* __restrict__ pooled) {
  int tid = threadIdx.x;
  float loc[8] = {0, 0, 0, 0, 0, 0, 0, 0};
  for (int r = blockIdx.x * 256 + tid; r < 20000; r += 80 * 256) {
    float t[8];
    ld8(pp + (size_t)r * 8, t);
    #pragma unroll
    for (int h = 0; h < 8; ++h) loc[h] += t[h];
  }
  #pragma unroll
  for (int off = 1; off < 64; off <<= 1)
    #pragma unroll
    for (int h = 0; h < 8; ++h) loc[h] += __shfl_xor(loc[h], off);
  __shared__ float sred[4][8];
  int wave = tid >> 6, lane = tid & 63;
  if (lane == 0) {
    #pragma unroll
    for (int h = 0; h < 8; ++h) sred[wave][h] = loc[h];
  }
  __syncthreads();
  if (tid < 8) {
    atomicAdd(&pooled[tid], sred[0][tid] + sred[1][tid] + sred[2][tid] + sred[3][tid]);
  }
}

// ---------------- head softmax weights ----------------
__global__ __launch_bounds__(256) void headw_kernel(const float* __restrict__ pooled,
    const float* __restrict__ b_gat, const float* __restrict__ conv_w,
    const float* __restrict__ conv_b, float* __restrict__ wsoft) {
  __shared__ float sb[8];
  int t = threadIdx.x;
  float v = 0.f;
  #pragma unroll
  for (int j = 0; j < 8; ++j) v += b_gat[t * 8 + j];
  #pragma unroll
  for (int off = 1; off < 32; off <<= 1) v += __shfl_xor(v, off);
  if ((t & 31) == 0 && t < 256) sb[t >> 5] = v;
  __syncthreads();
  if (t == 0) {
    const float invNC = 1.0f / (20000.0f * 256.0f);
    float g[8];
    float mx = -1e30f;
    #pragma unroll
    for (int h = 0; h < 8; ++h) {
      float pm = (pooled[h] + 20000.0f * sb[h]) * invNC;
      float gv = pm * conv_w[0] + conv_b[0];
      gv = fmaxf(gv, 0.f);
      g[h] = gv;
      mx = fmaxf(mx, gv);
    }
    float ssum = 0.f;
    #pragma unroll
    for (int h = 0; h < 8; ++h) { g[h] = __expf(g[h] - mx); ssum += g[h]; }
    #pragma unroll
    for (int h = 0; h < 8; ++h) wsoft[h] = g[h] / ssum;
  }
}

// fb[c] = sum_h wsoft[h] * b_gat[h*256+c]
__global__ void fb_kernel(const float* __restrict__ b_gat, const float* __restrict__ wsoft,
                          float* __restrict__ fb) {
  int c = threadIdx.x;
  float a = 0.f;
  #pragma unroll
  for (int h = 0; h < 8; ++h) a += wsoft[h] * b_gat[h * 256 + c];
  fb[c] = a;
}

extern "C" void kernel_launch(void* const* d_in, const int* in_sizes, int n_in,
                              void* d_out, int out_size, void* d_ws, size_t ws_size,
                              hipStream_t stream) {
  (void)in_sizes; (void)n_in; (void)out_size; (void)ws_size;
  const float* x      = (const float*)d_in[0];
  const int*   ei     = (const int*)d_in[1];
  const float* W_gat  = (const float*)d_in[2];
  const float* att_s  = (const float*)d_in[3];
  const float* att_d  = (const float*)d_in[4];
  const float* b_gat  = (const float*)d_in[5];
  const float* conv_w = (const float*)d_in[6];
  const float* conv_b = (const float*)d_in[7];
  const float* W_lin  = (const float*)d_in[8];
  const float* b_lin  = (const float*)d_in[9];
  float* out = (float*)d_out;

  char* p = (char*)d_ws;
  size_t off = 0;
  auto alloc = [&](size_t bytes) -> void* {
    void* r = p + off;
    off = (off + bytes + 255) & ~(size_t)255;
    return r;
  };
  short* x_bf   = (short*)alloc((size_t)20000 * 256 * 2);  // reused as Hf after alphaz
  short* wmixT  = (short*)alloc((size_t)256 * 2048 * 2);
  short* wlT    = (short*)alloc((size_t)256 * 256 * 2);
  float* ws_s   = (float*)alloc(2048 * 4);
  float* ws_d   = (float*)alloc(2048 * 4);
  float* ws_r   = (float*)alloc(2048 * 4);
  float* a_s    = (float*)alloc((size_t)20000 * 8 * 4);
  float* a_d    = (float*)alloc((size_t)20000 * 8 * 4);
  float* rs     = (float*)alloc((size_t)20000 * 8 * 4);
  int*   deg    = (int*)alloc(20000 * 4);
  float* pooled = (float*)alloc(8 * 4);
  float* wsoft  = (float*)alloc(8 * 4);
  float* fb     = (float*)alloc(256 * 4);
  int*   rowptr = (int*)alloc(20001 * 4);
  int*   cursor = (int*)alloc(20000 * 4);
  int*   csr    = (int*)alloc(200000 * 4);
  float* pp     = (float*)alloc((size_t)20000 * 8 * 4);
  short* u      = (short*)alloc((size_t)20000 * 2048 * 2);
  short* Hf     = x_bf;  // x_bf dead after alphaz; Hf written by gemm<2>

  hipMemsetAsync(deg, 0, 20000 * 4, stream);
  hipMemsetAsync(pooled, 0, 8 * 4, stream);

  transpose_kernel<<<dim3(8, 8), dim3(32, 8), 0, stream>>>(W_lin, wlT, 256, 250, 256);
  prepws_kernel<<<32, 256, 0, stream>>>(W_gat, att_s, att_d, ws_s, ws_d, ws_r);
  asd_kernel<<<625, 256, 0, stream>>>(x, ws_s, ws_d, ws_r, a_s, a_d, rs, x_bf);
  hist_kernel<<<782, 256, 0, stream>>>(ei, deg, 200000);
  scan_kernel<<<1, 1024, 0, stream>>>(deg, rowptr, cursor, 20000);
  scatter_kernel<<<782, 256, 0, stream>>>(ei, cursor, csr, 200000);
  alphaz_kernel<<<10000, 256, 0, stream>>>(x_bf, a_s, a_d, rs, rowptr, csr, u, pp);
  reduce_pp_kernel<<<80, 256, 0, stream>>>(pp, pooled);
  headw_kernel<<<1, 256, 0, stream>>>(pooled, b_gat, conv_w, conv_b, wsoft);
  wmix_kernel<<<dim3(8, 8, 8), dim3(32, 8), 0, stream>>>(W_gat, wsoft, wmixT);
  fb_kernel<<<1, 256, 0, stream>>>(b_gat, wsoft, fb);
  // Hf = relu(u @ Wmix + fb + x)  [20000x256 bf16], BK=128, 16 K-steps
  gemm_kernel<2><<<313, 256, 0, stream>>>(u, wmixT, 20000, 2048,
                                          Hf, nullptr, fb, x, 256);
  // out = Hf @ W_lin + b_lin  [20000x250 f32], BK=128, 2 K-steps
  gemm_kernel<1><<<313, 256, 0, stream>>>(Hf, wlT, 20000, 256,
                                          nullptr, out, b_lin, nullptr, 250);
}

// Round 12
// 200.576 us; speedup vs baseline: 1.3827x; 1.1134x over previous
//
#include <hip/hip_runtime.h>
#include <hip/hip_bf16.h>

// N=20000 nodes, E=200000 edges, H=8, C=256, IN=256, OUT=250, H*C=2048.
// R12: revert alphaz to R10 (R11 MFMA rewrite failed); consolidate launches
//      (prep1 = transpose+prepws+hist; headw+fb merged); coalesced x_bf write
//      in asd (register-buffered 64B per thread); 2-edge unroll in alphaz.

typedef __attribute__((ext_vector_type(8))) short short8v;
typedef __attribute__((ext_vector_type(4))) float float4v;

__device__ __forceinline__ unsigned f2bfu(float f) {
  unsigned u = __float_as_uint(f);
  return (u + 0x7fffu + ((u >> 16) & 1u)) >> 16;  // RNE f32 -> bf16
}
__device__ __forceinline__ float bfu_lo(unsigned u) { return __uint_as_float(u << 16); }
__device__ __forceinline__ float bfu_hi(unsigned u) { return __uint_as_float(u & 0xffff0000u); }
__device__ __forceinline__ unsigned pack2(float a, float b) { return f2bfu(a) | (f2bfu(b) << 16); }

__device__ __forceinline__ void ld8(const float* p, float* v) {
  float4 a = ((const float4*)p)[0], b = ((const float4*)p)[1];
  v[0] = a.x; v[1] = a.y; v[2] = a.z; v[3] = a.w;
  v[4] = b.x; v[5] = b.y; v[6] = b.z; v[7] = b.w;
}
__device__ __forceinline__ void ld4(const float* p, float* v) {
  float4 a = ((const float4*)p)[0];
  v[0] = a.x; v[1] = a.y; v[2] = a.z; v[3] = a.w;
}

__device__ __forceinline__ float bcast(float x, int e) {
  return __uint_as_float((unsigned)__builtin_amdgcn_readlane((int)__float_as_uint(x), e));
}

__device__ __forceinline__ void gll16(const void* g, void* l) {
  __builtin_amdgcn_global_load_lds(
      (__attribute__((address_space(1))) void*)const_cast<void*>(g),
      (__attribute__((address_space(3))) void*)(l), 16, 0, 0);
}

// ---------------- prep1: transpose(W_lin) + prepws + hist, block-range dispatch --------
__global__ __launch_bounds__(256) void prep1_kernel(
    const float* __restrict__ W_lin, short* __restrict__ wlT,
    const float* __restrict__ W, const float* __restrict__ att_s,
    const float* __restrict__ att_d, float* __restrict__ ws_s,
    float* __restrict__ ws_d, float* __restrict__ ws_r,
    const int* __restrict__ ei, int* __restrict__ deg) {
  __shared__ float smem[4096];  // 16 KB, reused per branch
  int b = blockIdx.x;
  int t = threadIdx.x;
  if (b < 64) {
    // wlT[c][r] = bf16(W_lin[r][c]); zero-pad c in [250,256)
    float (*tile)[33] = (float(*)[33])smem;
    int tx = t & 31, ty = t >> 5;
    int c0 = (b & 7) * 32, r0 = (b >> 3) * 32;
    #pragma unroll
    for (int j = ty; j < 32; j += 8) {
      int r = r0 + j, c = c0 + tx;
      tile[j][tx] = (c < 250) ? W_lin[(size_t)r * 250 + c] : 0.f;
    }
    __syncthreads();
    #pragma unroll
    for (int j = ty; j < 32; j += 8) {
      int c = c0 + j, r = r0 + tx;
      wlT[(size_t)c * 256 + r] = (short)f2bfu(tile[tx][j]);
    }
  } else if (b < 96) {
    // prepws: ws_s[k*8+h] = sum_c W[k][h*256+c]*att_s[h][c]; ws_r = row-chunk sum
    float* sas = smem;
    float* sad = smem + 2048;
    for (int i = t; i < 2048; i += 256) { sas[i] = att_s[i]; sad[i] = att_d[i]; }
    __syncthreads();
    int kk = t >> 5, h = (t >> 2) & 7, q = t & 3;
    int k = (b - 64) * 8 + kk;           // k in [0,256)
    const float4* wr = (const float4*)(W + (size_t)k * 2048 + h * 256 + q * 64);
    const float* as = sas + h * 256 + q * 64;
    const float* ad = sad + h * 256 + q * 64;
    float s = 0.f, dd = 0.f, r = 0.f;
    #pragma unroll
    for (int c4 = 0; c4 < 16; ++c4) {
      float4 wv = wr[c4];
      int c = c4 * 4;
      s  += wv.x * as[c] + wv.y * as[c + 1] + wv.z * as[c + 2] + wv.w * as[c + 3];
      dd += wv.x * ad[c] + wv.y * ad[c + 1] + wv.z * ad[c + 2] + wv.w * ad[c + 3];
      r  += wv.x + wv.y + wv.z + wv.w;
    }
    #pragma unroll
    for (int off = 1; off < 4; off <<= 1) {
      s += __shfl_xor(s, off);
      dd += __shfl_xor(dd, off);
      r += __shfl_xor(r, off);
    }
    if (q == 0) {
      int g = k * 8 + h;
      ws_s[g] = s;
      ws_d[g] = dd;
      ws_r[g] = r;
    }
  } else {
    int e = (b - 96) * 256 + t;
    if (e < 200000) atomicAdd(&deg[ei[200000 + e]], 1);
  }
}

// a_s/a_d/rs[n][h] = x[n,:] . ws_*[:,h] (f32 exact); x_bf written coalesced:
// thread (node,h) owns chunks k4 in [8h, 8h+8) -> 64B register buffer -> 4x int4.
__global__ __launch_bounds__(256) void asd_kernel(const float* __restrict__ x,
    const float* __restrict__ ws_s, const float* __restrict__ ws_d,
    const float* __restrict__ ws_r, float* __restrict__ a_s,
    float* __restrict__ a_d, float* __restrict__ rs, short* __restrict__ x_bf) {
  __shared__ float ls[2048], ld2[2048], lr[2048];
  int tid = threadIdx.x;
  for (int i = tid; i < 2048; i += 256) { ls[i] = ws_s[i]; ld2[i] = ws_d[i]; lr[i] = ws_r[i]; }
  __syncthreads();
  int node = blockIdx.x * 32 + (tid >> 3);
  int h = tid & 7;
  const float4* xr = (const float4*)(x + (size_t)node * 256);
  float as = 0.f, ad = 0.f, rr = 0.f;
  #pragma unroll 1
  for (int g = 0; g < 8; ++g) {
    bool own = (g == h);
    int bufi[16];
    #pragma unroll
    for (int j = 0; j < 8; ++j) {
      int k4 = g * 8 + j;
      float4 v = xr[k4];
      int k8 = k4 * 32 + h;
      as += v.x * ls[k8] + v.y * ls[k8 + 8] + v.z * ls[k8 + 16] + v.w * ls[k8 + 24];
      ad += v.x * ld2[k8] + v.y * ld2[k8 + 8] + v.z * ld2[k8 + 16] + v.w * ld2[k8 + 24];
      rr += v.x * lr[k8] + v.y * lr[k8 + 8] + v.z * lr[k8 + 16] + v.w * lr[k8 + 24];
      bufi[2 * j] = (int)pack2(v.x, v.y);
      bufi[2 * j + 1] = (int)pack2(v.z, v.w);
    }
    if (own) {
      int4* dst = (int4*)(x_bf + (size_t)node * 256 + h * 32);
      dst[0] = make_int4(bufi[0], bufi[1], bufi[2], bufi[3]);
      dst[1] = make_int4(bufi[4], bufi[5], bufi[6], bufi[7]);
      dst[2] = make_int4(bufi[8], bufi[9], bufi[10], bufi[11]);
      dst[3] = make_int4(bufi[12], bufi[13], bufi[14], bufi[15]);
    }
  }
  a_s[node * 8 + h] = as;
  a_d[node * 8 + h] = ad;
  rs[node * 8 + h] = rr;
}

// ---------------- bf16 MFMA GEMM (64x256 tile, BK=128, 4 waves) ----------------
// C[M][256] = A[M][K] * BT[256][K]^T ; wave w owns output cols w*64..w*64+63.
// LDS [row][128] shorts, row stride 256B; chunk XOR (row&7) balances b128 reads.
// EPI=1: f32 store + bias, col<Nout.  EPI=2: bf16 store of relu(acc+bias+xres).
template <int EPI>
__global__ __launch_bounds__(256, 2) void gemm_kernel(
    const short* __restrict__ A, const short* __restrict__ BT,
    int M, int K,
    short* __restrict__ Cb, float* __restrict__ Cf,
    const float* __restrict__ bias, const float* __restrict__ xres, int Nout) {
  __shared__ short lA[64 * 128];    // 16 KB
  __shared__ short lB[256 * 128];   // 64 KB
  int tid = threadIdx.x;
  int wave = tid >> 6, lane = tid & 63;
  int m0 = blockIdx.x << 6;
  int lr = lane & 15, lq = lane >> 4;
  int lrow4 = lane >> 4;
  int pch = lane & 15;

  float4v acc[4][4];
  #pragma unroll
  for (int i = 0; i < 4; ++i)
    #pragma unroll
    for (int j = 0; j < 4; ++j) acc[i][j] = (float4v){0.f, 0.f, 0.f, 0.f};

  int offA[4];
  #pragma unroll
  for (int it = 0; it < 4; ++it) {
    int rowl = wave * 16 + it * 4 + lrow4;
    int grow = m0 + rowl;
    if (grow >= M) grow = M - 1;
    int logical = pch ^ (rowl & 7);
    offA[it] = grow * K + logical * 8;
  }
  int offB[16];
  #pragma unroll
  for (int it = 0; it < 16; ++it) {
    int rowb = wave * 64 + it * 4 + lrow4;
    int logical = pch ^ (rowb & 7);
    offB[it] = rowb * K + logical * 8;
  }

  int nk = K >> 7;
  for (int t = 0; t < nk; ++t) {
    int k0 = t << 7;
    __syncthreads();
    #pragma unroll
    for (int it = 0; it < 4; ++it)
      gll16(A + offA[it] + k0, lA + (wave * 16 + it * 4) * 128);
    #pragma unroll
    for (int it = 0; it < 16; ++it)
      gll16(BT + offB[it] + k0, lB + (wave * 64 + it * 4) * 128);
    __syncthreads();
    #pragma unroll
    for (int ks = 0; ks < 4; ++ks) {
      int phys = ((ks * 4 + lq) ^ (lr & 7)) * 8;
      short8v af[4], bfv[4];
      #pragma unroll
      for (int i = 0; i < 4; ++i)
        af[i] = *(const short8v*)(lA + (i * 16 + lr) * 128 + phys);
      #pragma unroll
      for (int j = 0; j < 4; ++j)
        bfv[j] = *(const short8v*)(lB + (wave * 64 + j * 16 + lr) * 128 + phys);
      #pragma unroll
      for (int i = 0; i < 4; ++i)
        #pragma unroll
        for (int j = 0; j < 4; ++j)
          acc[i][j] = __builtin_amdgcn_mfma_f32_16x16x32_bf16(af[i], bfv[j], acc[i][j], 0, 0, 0);
    }
  }

  #pragma unroll
  for (int i = 0; i < 4; ++i) {
    #pragma unroll
    for (int jj = 0; jj < 4; ++jj) {
      int row = m0 + i * 16 + lq * 4 + jj;
      if (row >= M) continue;
      #pragma unroll
      for (int j = 0; j < 4; ++j) {
        int col = wave * 64 + j * 16 + lr;
        float v = acc[i][j][jj];
        if (EPI == 1) {
          if (col < Nout) Cf[(size_t)row * Nout + col] = v + bias[col];
        } else {
          float o = v + bias[col] + xres[(size_t)row * 256 + col];
          Cb[(size_t)row * 256 + col] = (short)f2bfu(fmaxf(o, 0.f));
        }
      }
    }
  }
}

// ---------------- CSR scan / scatter ----------------

__global__ __launch_bounds__(1024) void scan_kernel(const int* __restrict__ deg,
                                                    int* __restrict__ rowptr,
                                                    int* __restrict__ cursor, int n) {
  __shared__ int part[1024];
  int t = threadIdx.x;
  int base = t * 20;
  int loc[20];
  int run = 0;
  #pragma unroll
  for (int j = 0; j < 20; ++j) {
    int idx = base + j;
    int v = (idx < n) ? deg[idx] : 0;
    loc[j] = run;
    run += v;
  }
  part[t] = run;
  __syncthreads();
  for (int off = 1; off < 1024; off <<= 1) {
    int add = (t >= off) ? part[t - off] : 0;
    __syncthreads();
    part[t] += add;
    __syncthreads();
  }
  int off0 = (t > 0) ? part[t - 1] : 0;
  #pragma unroll
  for (int j = 0; j < 20; ++j) {
    int idx = base + j;
    if (idx < n) {
      int v = off0 + loc[j];
      rowptr[idx] = v;
      cursor[idx] = v;
    }
  }
  if (t == 1023) rowptr[n] = part[1023];
}

__global__ void scatter_kernel(const int* __restrict__ ei, int* __restrict__ cursor,
                               int* __restrict__ csr_src, int E) {
  int e = blockIdx.x * 256 + threadIdx.x;
  if (e < E) {
    int pos = atomicAdd(&cursor[ei[E + e]], 1);
    csr_src[pos] = ei[e];
  }
}

// ---------------- fused softmax + z-aggregate, single pass ----------------
// 2 waves per dst; wave handles 4 heads. No-max softmax, deferred normalization.
__global__ __launch_bounds__(256) void alphaz_kernel(
    const short* __restrict__ x_bf, const float* __restrict__ a_s,
    const float* __restrict__ a_d, const float* __restrict__ rs,
    const int* __restrict__ rowptr, const int* __restrict__ csr,
    short* __restrict__ u, float* __restrict__ pp) {
  int gw = blockIdx.x * 4 + (threadIdx.x >> 6);
  int d = gw >> 1;
  int wh = (gw & 1) * 4;          // head offset for this wave
  int lane = threadIdx.x & 63;
  int beg = rowptr[d];
  int deg = rowptr[d + 1] - beg;

  float ad[4];
  ld4(a_d + (size_t)d * 8 + wh, ad);

  float acc[4][4];
  #pragma unroll
  for (int h = 0; h < 4; ++h)
    #pragma unroll
    for (int j = 0; j < 4; ++j) acc[h][j] = 0.f;
  float s4[4], p4[4];

  // self edge
  {
    float t[4], rsv[4];
    ld4(a_s + (size_t)d * 8 + wh, t);
    ld4(rs + (size_t)d * 8 + wh, rsv);
    uint2 v = *(const uint2*)(x_bf + (size_t)d * 256 + lane * 4);
    float xv0 = bfu_lo(v.x), xv1 = bfu_hi(v.x), xv2 = bfu_lo(v.y), xv3 = bfu_hi(v.y);
    float lz = (lane == 0) ? 1.f : 0.f;
    #pragma unroll
    for (int h = 0; h < 4; ++h) {
      float e = t[h] + ad[h];
      e = (e > 0.f) ? e : 0.2f * e;
      float ex = __expf(e);
      acc[h][0] += ex * xv0;
      acc[h][1] += ex * xv1;
      acc[h][2] += ex * xv2;
      acc[h][3] += ex * xv3;
      s4[h] = ex * lz;
      p4[h] = ex * rsv[h] * lz;
    }
  }

  for (int base = 0; base < deg; base += 64) {
    int i = base + lane;
    bool act = i < deg;
    int src = act ? csr[beg + i] : 0;
    // lane-parallel: 4 exps for THIS lane's edge only
    float ex[4];
    {
      float t[4], rsv[4];
      ld4(a_s + (size_t)src * 8 + wh, t);
      ld4(rs + (size_t)src * 8 + wh, rsv);
      #pragma unroll
      for (int h = 0; h < 4; ++h) {
        float e = t[h] + ad[h];
        e = (e > 0.f) ? e : 0.2f * e;
        float xx = __expf(e);
        ex[h] = act ? xx : 0.f;
        s4[h] += ex[h];
        p4[h] += ex[h] * rsv[h];
      }
    }
    // wave-serial accumulate, 2-edge unrolled; broadcast via v_readlane
    int cnt = deg - base;
    if (cnt > 64) cnt = 64;
    int e = 0;
    for (; e + 1 < cnt; e += 2) {
      int s0 = __builtin_amdgcn_readlane(src, e);
      int s1 = __builtin_amdgcn_readlane(src, e + 1);
      uint2 v0 = *(const uint2*)(x_bf + (size_t)s0 * 256 + lane * 4);
      uint2 v1 = *(const uint2*)(x_bf + (size_t)s1 * 256 + lane * 4);
      float q0[4], q1[4];
      #pragma unroll
      for (int h = 0; h < 4; ++h) { q0[h] = bcast(ex[h], e); q1[h] = bcast(ex[h], e + 1); }
      float a0 = bfu_lo(v0.x), a1 = bfu_hi(v0.x), a2 = bfu_lo(v0.y), a3 = bfu_hi(v0.y);
      float b0 = bfu_lo(v1.x), b1 = bfu_hi(v1.x), b2 = bfu_lo(v1.y), b3 = bfu_hi(v1.y);
      #pragma unroll
      for (int h = 0; h < 4; ++h) {
        acc[h][0] += q0[h] * a0 + q1[h] * b0;
        acc[h][1] += q0[h] * a1 + q1[h] * b1;
        acc[h][2] += q0[h] * a2 + q1[h] * b2;
        acc[h][3] += q0[h] * a3 + q1[h] * b3;
      }
    }
    if (e < cnt) {
      int s0 = __builtin_amdgcn_readlane(src, e);
      uint2 v0 = *(const uint2*)(x_bf + (size_t)s0 * 256 + lane * 4);
      float q0[4];
      #pragma unroll
      for (int h = 0; h < 4; ++h) q0[h] = bcast(ex[h], e);
      float a0 = bfu_lo(v0.x), a1 = bfu_hi(v0.x), a2 = bfu_lo(v0.y), a3 = bfu_hi(v0.y);
      #pragma unroll
      for (int h = 0; h < 4; ++h) {
        acc[h][0] += q0[h] * a0;
        acc[h][1] += q0[h] * a1;
        acc[h][2] += q0[h] * a2;
        acc[h][3] += q0[h] * a3;
      }
    }
  }

  // reduce s/p across lanes, normalize, write out
  #pragma unroll
  for (int off = 1; off < 64; off <<= 1)
    #pragma unroll
    for (int h = 0; h < 4; ++h) {
      s4[h] += __shfl_xor(s4[h], off);
      p4[h] += __shfl_xor(p4[h], off);
    }
  float inv[4];
  #pragma unroll
  for (int h = 0; h < 4; ++h) inv[h] = 1.f / (s4[h] + 1e-16f);
  #pragma unroll
  for (int h = 0; h < 4; ++h) {
    uint2 ov;
    ov.x = pack2(acc[h][0] * inv[h], acc[h][1] * inv[h]);
    ov.y = pack2(acc[h][2] * inv[h], acc[h][3] * inv[h]);
    *(uint2*)(u + (size_t)d * 2048 + (wh + h) * 256 + lane * 4) = ov;
  }
  if (lane == 0) {
    float4 pn;
    pn.x = p4[0] * inv[0];
    pn.y = p4[1] * inv[1];
    pn.z = p4[2] * inv[2];
    pn.w = p4[3] * inv[3];
    *(float4*)(pp + (size_t)d * 8 + wh) = pn;
  }
}

// ---------------- pooled reduction ----------------
__global__ __launch_bounds__(256) void reduce_pp_kernel(const float* __restrict__ pp,
                                                        float* __restrict__ pooled) {
  int tid = threadIdx.x;
  float loc[8] = {0, 0, 0, 0, 0, 0, 0, 0};
  for (int r = blockIdx.x * 256 + tid; r < 20000; r += 80 * 256) {
    float t[8];
    ld8(pp + (size_t)r * 8, t);
    #pragma unroll
    for (int h = 0; h < 8; ++h) loc[h] += t[h];
  }
  #pragma unroll
  for (int off = 1; off < 64; off <<= 1)
    #pragma unroll
    for (int h = 0; h < 8; ++h) loc[h] += __shfl_xor(loc[h], off);
  __shared__ float sred[4][8];
  int wave = tid >> 6, lane = tid & 63;
  if (lane == 0) {
    #pragma unroll
    for (int h = 0; h < 8; ++h) sred[wave][h] = loc[h];
  }
  __syncthreads();
  if (tid < 8) {
    atomicAdd(&pooled[tid], sred[0][tid] + sred[1][tid] + sred[2][tid] + sred[3][tid]);
  }
}

// ---------------- head softmax weights + fused bias (fb) ----------------
__global__ __launch_bounds__(256) void headwfb_kernel(const float* __restrict__ pooled,
    const float* __restrict__ b_gat, const float* __restrict__ conv_w,
    const float* __restrict__ conv_b, float* __restrict__ wsoft,
    float* __restrict__ fb) {
  __shared__ float sb[8];
  __shared__ float sw[8];
  int t = threadIdx.x;
  float v = 0.f;
  #pragma unroll
  for (int j = 0; j < 8; ++j) v += b_gat[t * 8 + j];
  #pragma unroll
  for (int off = 1; off < 32; off <<= 1) v += __shfl_xor(v, off);
  if ((t & 31) == 0) sb[t >> 5] = v;
  __syncthreads();
  if (t == 0) {
    const float invNC = 1.0f / (20000.0f * 256.0f);
    float g[8];
    float mx = -1e30f;
    #pragma unroll
    for (int h = 0; h < 8; ++h) {
      float pm = (pooled[h] + 20000.0f * sb[h]) * invNC;
      float gv = pm * conv_w[0] + conv_b[0];
      gv = fmaxf(gv, 0.f);
      g[h] = gv;
      mx = fmaxf(mx, gv);
    }
    float ssum = 0.f;
    #pragma unroll
    for (int h = 0; h < 8; ++h) { g[h] = __expf(g[h] - mx); ssum += g[h]; }
    #pragma unroll
    for (int h = 0; h < 8; ++h) {
      float w = g[h] / ssum;
      wsoft[h] = w;
      sw[h] = w;
    }
  }
  __syncthreads();
  float a = 0.f;
  #pragma unroll
  for (int h = 0; h < 8; ++h) a += sw[h] * b_gat[h * 256 + t];
  fb[t] = a;
}

// wmixT[c][h*256+k] = bf16(wsoft[h] * W_gat[k][h*256+c])  (scaled per-head transpose)
__global__ void wmix_kernel(const float* __restrict__ W, const float* __restrict__ wsoft,
                            short* __restrict__ out) {
  __shared__ float tile[32][33];
  int tx = threadIdx.x, ty = threadIdx.y;
  int h = blockIdx.z;
  float wh = wsoft[h];
  int c0 = blockIdx.x * 32, k0 = blockIdx.y * 32;
  #pragma unroll
  for (int j = ty; j < 32; j += 8)
    tile[j][tx] = W[(size_t)(k0 + j) * 2048 + h * 256 + c0 + tx];
  __syncthreads();
  #pragma unroll
  for (int j = ty; j < 32; j += 8)
    out[(size_t)(c0 + j) * 2048 + h * 256 + k0 + tx] = (short)f2bfu(wh * tile[tx][j]);
}

extern "C" void kernel_launch(void* const* d_in, const int* in_sizes, int n_in,
                              void* d_out, int out_size, void* d_ws, size_t ws_size,
                              hipStream_t stream) {
  (void)in_sizes; (void)n_in; (void)out_size; (void)ws_size;
  const float* x      = (const float*)d_in[0];
  const int*   ei     = (const int*)d_in[1];
  const float* W_gat  = (const float*)d_in[2];
  const float* att_s  = (const float*)d_in[3];
  const float* att_d  = (const float*)d_in[4];
  const float* b_gat  = (const float*)d_in[5];
  const float* conv_w = (const float*)d_in[6];
  const float* conv_b = (const float*)d_in[7];
  const float* W_lin  = (const float*)d_in[8];
  const float* b_lin  = (const float*)d_in[9];
  float* out = (float*)d_out;

  char* p = (char*)d_ws;
  size_t off = 0;
  auto alloc = [&](size_t bytes) -> void* {
    void* r = p + off;
    off = (off + bytes + 255) & ~(size_t)255;
    return r;
  };
  short* x_bf   = (short*)alloc((size_t)20000 * 256 * 2);  // reused as Hf after alphaz
  short* wmixT  = (short*)alloc((size_t)256 * 2048 * 2);
  short* wlT    = (short*)alloc((size_t)256 * 256 * 2);
  float* ws_s   = (float*)alloc(2048 * 4);
  float* ws_d   = (float*)alloc(2048 * 4);
  float* ws_r   = (float*)alloc(2048 * 4);
  float* a_s    = (float*)alloc((size_t)20000 * 8 * 4);
  float* a_d    = (float*)alloc((size_t)20000 * 8 * 4);
  float* rs     = (float*)alloc((size_t)20000 * 8 * 4);
  int*   deg    = (int*)alloc(20000 * 4);
  float* pooled = (float*)alloc(8 * 4);
  float* wsoft  = (float*)alloc(8 * 4);
  float* fb     = (float*)alloc(256 * 4);
  int*   rowptr = (int*)alloc(20001 * 4);
  int*   cursor = (int*)alloc(20000 * 4);
  int*   csr    = (int*)alloc(200000 * 4);
  float* pp     = (float*)alloc((size_t)20000 * 8 * 4);
  short* u      = (short*)alloc((size_t)20000 * 2048 * 2);
  short* Hf     = x_bf;  // x_bf dead after alphaz; Hf written by gemm<2>

  hipMemsetAsync(deg, 0, 20000 * 4, stream);
  hipMemsetAsync(pooled, 0, 8 * 4, stream);

  // prep1: blocks [0,64) transpose W_lin; [64,96) prepws; [96,878) hist
  prep1_kernel<<<878, 256, 0, stream>>>(W_lin, wlT, W_gat, att_s, att_d,
                                        ws_s, ws_d, ws_r, ei, deg);
  scan_kernel<<<1, 1024, 0, stream>>>(deg, rowptr, cursor, 20000);
  asd_kernel<<<625, 256, 0, stream>>>(x, ws_s, ws_d, ws_r, a_s, a_d, rs, x_bf);
  scatter_kernel<<<782, 256, 0, stream>>>(ei, cursor, csr, 200000);
  alphaz_kernel<<<10000, 256, 0, stream>>>(x_bf, a_s, a_d, rs, rowptr, csr, u, pp);
  reduce_pp_kernel<<<80, 256, 0, stream>>>(pp, pooled);
  headwfb_kernel<<<1, 256, 0, stream>>>(pooled, b_gat, conv_w, conv_b, wsoft, fb);
  wmix_kernel<<<dim3(8, 8, 8), dim3(32, 8), 0, stream>>>(W_gat, wsoft, wmixT);
  // Hf = relu(u @ Wmix + fb + x)  [20000x256 bf16], BK=128, 16 K-steps
  gemm_kernel<2><<<313, 256, 0, stream>>>(u, wmixT, 20000, 2048,
                                          Hf, nullptr, fb, x, 256);
  // out = Hf @ W_lin + b_lin  [20000x250 f32], BK=128, 2 K-steps
  gemm_kernel<1><<<313, 256, 0, stream>>>(Hf, wlT, 20000, 256,
                                          nullptr, out, b_lin, nullptr, 250);
}